// Round 9
// baseline (9694.307 us; speedup 1.0000x reference)
//
#include <hip/hip_runtime.h>

#define NN1 60000
#define EE1 600000
#define NN2 20000
#define EE2 150000
#define AA  60000

__device__ __forceinline__ float sigf(float x){ return 1.f/(1.f+expf(-x)); }

// ---------- elementwise ----------
__global__ void k_relu(float* a, int n){
  int i = blockIdx.x*blockDim.x + threadIdx.x;
  if (i < n) a[i] = fmaxf(a[i], 0.f);
}
__global__ void k_copy(const float* __restrict__ a, float* __restrict__ o, int n){
  int i = blockIdx.x*blockDim.x + threadIdx.x;
  if (i < n) o[i] = a[i];
}

// ---------- edge type ----------
__global__ void k_etype(const float* __restrict__ ea, int* __restrict__ etype, int E){
  int e = blockIdx.x*blockDim.x + threadIdx.x;
  if (e >= E) return;
  const float* p = ea + (size_t)e*10;
  float best = p[0]; int bi = 0;
  #pragma unroll
  for (int k = 1; k < 4; ++k){ float v = p[k]; if (v > best){ best = v; bi = k; } }
  etype[e] = bi;
}

__global__ void k_coeff(const float* __restrict__ nt, const int* __restrict__ node_type,
                        float* __restrict__ coeff, int N){
  int n = blockIdx.x*blockDim.x + threadIdx.x;
  if (n < N) coeff[n] = nt[node_type[n]];
}

// ---------- batch row pointers (batch sorted ascending) ----------
__global__ void k_batchptr(const int* __restrict__ batch, int* __restrict__ rb, int N, int B){
  int n = blockIdx.x*blockDim.x + threadIdx.x;
  if (n >= N) return;
  int b = batch[n];
  if (n == 0){ for (int g = 0; g <= b; ++g) rb[g] = 0; }
  else {
    int pb = batch[n-1];
    for (int g = pb+1; g <= b; ++g) rb[g] = n;
  }
  if (n == N-1){ for (int g = b+1; g <= B; ++g) rb[g] = N; }
}

// ---------- GRU weight transpose: wih[l][j][c] -> wihT[l][t][c][d], j=64t+d ----------
__global__ void k_wtrans(const float* __restrict__ wih, const float* __restrict__ whh,
                         float* __restrict__ wihT, float* __restrict__ whhT){
  int idx = blockIdx.x*256 + threadIdx.x;   // 5*192*64 = 61440
  if (idx >= 5*192*64) return;
  int l = idx / 12288, r = idx % 12288;
  int j = r >> 6, c = r & 63;
  int t = j >> 6, d = j & 63;
  int dst = l*12288 + t*4096 + c*64 + d;
  wihT[dst] = wih[idx];
  whhT[dst] = whh[idx];
}

// ---------- CSR build ----------
__global__ void k_hist(const int* __restrict__ dst, const int* __restrict__ etype,
                       int* __restrict__ cnt, int E, int N, int tkey){
  int e = blockIdx.x*blockDim.x + threadIdx.x;
  if (e >= E) return;
  int t = etype ? etype[e] : 0;
  int key = tkey ? (t*N + dst[e]) : dst[e];
  atomicAdd(&cnt[key], 1);
}
__global__ void k_chunksum(const int* __restrict__ cnt, int* __restrict__ csum, int M){
  __shared__ int sh[256];
  int base = blockIdx.x*1024;
  int s = 0;
  for (int i = threadIdx.x; i < 1024; i += 256){
    int idx = base + i;
    if (idx < M) s += cnt[idx];
  }
  sh[threadIdx.x] = s;
  __syncthreads();
  for (int o = 128; o; o >>= 1){
    if (threadIdx.x < o) sh[threadIdx.x] += sh[threadIdx.x + o];
    __syncthreads();
  }
  if (threadIdx.x == 0) csum[blockIdx.x] = sh[0];
}
__global__ void k_chunkscan(int* __restrict__ csum, int nchunk){
  __shared__ int sh[256];
  int i = threadIdx.x;
  int v = (i < nchunk) ? csum[i] : 0;
  sh[i] = v; __syncthreads();
  for (int o = 1; o < 256; o <<= 1){
    int y = (i >= o) ? sh[i-o] : 0;
    __syncthreads();
    sh[i] += y;
    __syncthreads();
  }
  if (i < nchunk) csum[i] = sh[i] - v;
  if (i == 255) csum[nchunk] = sh[255];
}
__global__ void k_chunkapply(const int* __restrict__ cnt, const int* __restrict__ csum,
                             int* __restrict__ R, int* __restrict__ cur, int M){
  __shared__ int sh[256];
  int base = blockIdx.x*1024;
  int i0 = base + threadIdx.x*4;
  int v[4]; int s = 0;
  #pragma unroll
  for (int k = 0; k < 4; ++k){ int idx = i0 + k; v[k] = (idx < M) ? cnt[idx] : 0; s += v[k]; }
  sh[threadIdx.x] = s; __syncthreads();
  for (int o = 1; o < 256; o <<= 1){
    int y = (threadIdx.x >= o) ? sh[threadIdx.x-o] : 0;
    __syncthreads();
    sh[threadIdx.x] += y;
    __syncthreads();
  }
  int run = csum[blockIdx.x] + sh[threadIdx.x] - s;
  #pragma unroll
  for (int k = 0; k < 4; ++k){
    int idx = i0 + k;
    if (idx < M){ R[idx] = run; cur[idx] = run; run += v[k]; }
  }
  if (threadIdx.x == 255 && base + 1024 >= M) R[M] = csum[blockIdx.x] + sh[255];
}
__global__ void k_scatter(const int* __restrict__ src, const int* __restrict__ dst,
                          const int* __restrict__ etype, int* __restrict__ cur,
                          int* __restrict__ ep, int E, int N, int tkey){
  int e = blockIdx.x*blockDim.x + threadIdx.x;
  if (e >= E) return;
  int t = etype ? etype[e] : 0;
  int key = tkey ? (t*N + dst[e]) : dst[e];
  int pos = atomicAdd(&cur[key], 1);
  ep[pos] = (t << 20) | src[e];
}

// ---------- transform: tr[t][n][d] = coeff[n] * sum_c X[n][c]*W[t][c][d] ----------
// 4 independent accumulators to break the FMA dependency chain
__global__ void k_transform4(const float* __restrict__ h, const float* __restrict__ W,
                             const float* __restrict__ coeff, float* __restrict__ tr, int N){
  int t = blockIdx.x >> 10, blk = blockIdx.x & 1023;
  int d = threadIdx.x & 63, sub = threadIdx.x >> 6;
  float wreg[64];
  const float* Wt = W + (size_t)t*4096;
  #pragma unroll
  for (int c = 0; c < 64; ++c) wreg[c] = Wt[c*64 + d];
  for (int n = blk*4 + sub; n < N; n += 4096){
    const float4* hr = (const float4*)(h + (size_t)n*64);
    float a0 = 0.f, a1 = 0.f, a2 = 0.f, a3 = 0.f;
    #pragma unroll
    for (int c = 0; c < 16; ++c){
      float4 v = hr[c];
      a0 = fmaf(v.x, wreg[4*c+0], a0);
      a1 = fmaf(v.y, wreg[4*c+1], a1);
      a2 = fmaf(v.z, wreg[4*c+2], a2);
      a3 = fmaf(v.w, wreg[4*c+3], a3);
    }
    float acc = (a0 + a1) + (a2 + a3);
    if (coeff) acc *= coeff[n];
    tr[((size_t)t*N + n)*64 + d] = acc;
  }
}

// ---------- GRU GEMMs, one launch: slabs 0-2 = aggr@wihT, 3-5 = h@whhT ----------
__global__ void k_gru_gemm(const float* __restrict__ aggr, const float* __restrict__ h,
                           const float* __restrict__ wihT, const float* __restrict__ whhT,
                           float* __restrict__ gb, int N){
  int slab = blockIdx.x >> 10, blk = blockIdx.x & 1023;
  int d = threadIdx.x & 63, sub = threadIdx.x >> 6;
  const float* X  = (slab < 3) ? aggr : h;
  const float* Wt = (slab < 3) ? (wihT + (size_t)slab*4096) : (whhT + (size_t)(slab-3)*4096);
  float wreg[64];
  #pragma unroll
  for (int c = 0; c < 64; ++c) wreg[c] = Wt[c*64 + d];
  for (int n = blk*4 + sub; n < N; n += 4096){
    const float4* hr = (const float4*)(X + (size_t)n*64);
    float a0 = 0.f, a1 = 0.f, a2 = 0.f, a3 = 0.f;
    #pragma unroll
    for (int c = 0; c < 16; ++c){
      float4 v = hr[c];
      a0 = fmaf(v.x, wreg[4*c+0], a0);
      a1 = fmaf(v.y, wreg[4*c+1], a1);
      a2 = fmaf(v.z, wreg[4*c+2], a2);
      a3 = fmaf(v.w, wreg[4*c+3], a3);
    }
    gb[((size_t)slab*N + n)*64 + d] = (a0 + a1) + (a2 + a3);
  }
}

// ---------- merged sweep ----------
__global__ void k_sweep_p(const float* __restrict__ tr, const int* __restrict__ R,
                          const int* __restrict__ ep, float* __restrict__ aggr, int N){
  int w = threadIdx.x >> 6, lane = threadIdx.x & 63;
  int d = blockIdx.x*4 + w;
  if (d >= N) return;
  int p = R[d], pend = R[d+1];
  float acc = 0.f;
  while (p < pend){
    int m = pend - p; if (m > 64) m = 64;
    int ev = (lane < m) ? ep[p + lane] : 0;
    for (int j = 0; j < m; ++j){
      int pk = __shfl(ev, j);
      int s = pk & 0xFFFFF, t = pk >> 20;
      acc += tr[((size_t)t*N + s)*64 + lane];
    }
    p += m;
  }
  aggr[(size_t)d*64 + lane] = acc;
}
__global__ void k_sweep(const float* __restrict__ tr, const int* __restrict__ R,
                        const int* __restrict__ ep, float* __restrict__ aggr,
                        int N, int first){
  int w = threadIdx.x >> 6, lane = threadIdx.x & 63;
  int d = blockIdx.x*4 + w;
  if (d >= N) return;
  int p = R[d], pend = R[d+1];
  float acc = first ? 0.f : aggr[(size_t)d*64 + lane];
  while (p < pend){
    int m = pend - p; if (m > 64) m = 64;
    int ev = (lane < m) ? ep[p + lane] : 0;
    for (int j = 0; j < m; ++j){
      int s = __shfl(ev, j) & 0xFFFFF;
      acc += tr[(size_t)s*64 + lane];
    }
    p += m;
  }
  aggr[(size_t)d*64 + lane] = acc;
}

// ---------- GRU finalize ----------
__global__ void k_gru_fin(const float* __restrict__ gb,
                          const float* __restrict__ bih, const float* __restrict__ bhh,
                          float* __restrict__ h, int N){
  int i = blockIdx.x*256 + threadIdx.x;     // over N*16 float4 slots
  if (i >= N*16) return;
  int q = i & 15;
  const float4* g4 = (const float4*)gb;
  size_t S = (size_t)N*16;
  float4 gi0 = g4[i], gi1 = g4[S + i], gi2 = g4[2*S + i];
  float4 gh0 = g4[3*S + i], gh1 = g4[4*S + i], gh2 = g4[5*S + i];
  const float4* bi4 = (const float4*)bih;
  const float4* bh4 = (const float4*)bhh;
  float4 bir = bi4[q],    bhr = bh4[q];
  float4 biz = bi4[16+q], bhz = bh4[16+q];
  float4 bin = bi4[32+q], bhn = bh4[32+q];
  float4* h4 = (float4*)h;
  float4 hv = h4[i];
  float4 out;
  {
    float r = sigf(gi0.x + gh0.x + bir.x + bhr.x);
    float z = sigf(gi1.x + gh1.x + biz.x + bhz.x);
    float nn = tanhf(gi2.x + bin.x + r*(gh2.x + bhn.x));
    out.x = (1.f - z)*nn + z*hv.x;
  }
  {
    float r = sigf(gi0.y + gh0.y + bir.y + bhr.y);
    float z = sigf(gi1.y + gh1.y + biz.y + bhz.y);
    float nn = tanhf(gi2.y + bin.y + r*(gh2.y + bhn.y));
    out.y = (1.f - z)*nn + z*hv.y;
  }
  {
    float r = sigf(gi0.z + gh0.z + bir.z + bhr.z);
    float z = sigf(gi1.z + gh1.z + biz.z + bhz.z);
    float nn = tanhf(gi2.z + bin.z + r*(gh2.z + bhn.z));
    out.z = (1.f - z)*nn + z*hv.z;
  }
  {
    float r = sigf(gi0.w + gh0.w + bir.w + bhr.w);
    float z = sigf(gi1.w + gh1.w + biz.w + bhz.w);
    float nn = tanhf(gi2.w + bin.w + r*(gh2.w + bhn.w));
    out.w = (1.f - z)*nn + z*hv.w;
  }
  h4[i] = out;
}

// ---------- GRU fallback ----------
__global__ void k_gru_old(const float* __restrict__ aggr, float* __restrict__ h,
                      const float* __restrict__ wih, const float* __restrict__ whh,
                      const float* __restrict__ bih, const float* __restrict__ bhh, int N){
  int j = threadIdx.x;
  float4 wi4[16], wh4[16];
  const float4* wisrc = (const float4*)(wih + (size_t)j*64);
  const float4* whsrc = (const float4*)(whh + (size_t)j*64);
  #pragma unroll
  for (int c = 0; c < 16; ++c){ wi4[c] = wisrc[c]; wh4[c] = whsrc[c]; }
  float bi = bih[j], bh = bhh[j];
  __shared__ float gi_s[192], gh_s[192];
  for (int n = blockIdx.x; n < N; n += gridDim.x){
    const float4* mr = (const float4*)(aggr + (size_t)n*64);
    const float4* hr = (const float4*)(h + (size_t)n*64);
    float ai = bi, ah = bh;
    #pragma unroll
    for (int c = 0; c < 16; ++c){
      float4 m4 = mr[c], h4 = hr[c];
      ai = fmaf(m4.x, wi4[c].x, ai); ah = fmaf(h4.x, wh4[c].x, ah);
      ai = fmaf(m4.y, wi4[c].y, ai); ah = fmaf(h4.y, wh4[c].y, ah);
      ai = fmaf(m4.z, wi4[c].z, ai); ah = fmaf(h4.z, wh4[c].z, ah);
      ai = fmaf(m4.w, wi4[c].w, ai); ah = fmaf(h4.w, wh4[c].w, ah);
    }
    gi_s[j] = ai; gh_s[j] = ah;
    __syncthreads();
    if (j < 64){
      float r  = sigf(gi_s[j]      + gh_s[j]);
      float z  = sigf(gi_s[64+j]   + gh_s[64+j]);
      float nn = tanhf(gi_s[128+j] + r*gh_s[128+j]);
      h[(size_t)n*64 + j] = (1.f - z)*nn + z*h[(size_t)n*64 + j];
    }
    __syncthreads();
  }
}

// ---------- batch norm over nodes ----------
__global__ void k_bnstats(const float* __restrict__ h, float* __restrict__ stats, int N){
  int c = threadIdx.x & 63;
  int g = threadIdx.x >> 6;
  float s = 0.f, s2 = 0.f;
  for (int n = blockIdx.x*4 + g; n < N; n += gridDim.x*4){
    float v = h[(size_t)n*64 + c]; s += v; s2 += v*v;
  }
  __shared__ float sh[4][64], sh2[4][64];
  sh[g][c] = s; sh2[g][c] = s2;
  __syncthreads();
  if (g == 0){
    float ts = sh[0][c]+sh[1][c]+sh[2][c]+sh[3][c];
    float t2 = sh2[0][c]+sh2[1][c]+sh2[2][c]+sh2[3][c];
    atomicAdd(&stats[c], ts); atomicAdd(&stats[64+c], t2);
  }
}
__global__ void k_bnapply(float* __restrict__ h, const float* __restrict__ stats,
                          const float* __restrict__ g, const float* __restrict__ b,
                          int N, int relu){
  int i = blockIdx.x*blockDim.x + threadIdx.x;
  if (i >= N*64) return;
  int c = i & 63;
  float inv = 1.f/(float)N;
  float mean = stats[c]*inv;
  float var  = stats[64+c]*inv - mean*mean;
  float y = (h[i]-mean)*rsqrtf(var + 1e-5f)*g[c] + b[c];
  if (relu) y = fmaxf(y, 0.f);
  h[i] = y;
}

// ---------- avg_pool ----------
__global__ void k_pool_acc(const float* __restrict__ h, const int* __restrict__ asrc,
                           const int* __restrict__ adst, float* __restrict__ h2,
                           float* __restrict__ cnt, int A){
  int i = blockIdx.x*blockDim.x + threadIdx.x;
  if (i >= A*64) return;
  int a = i >> 6, c = i & 63;
  int s = asrc[a], d = adst[a];
  atomicAdd(&h2[(size_t)d*64 + c], h[(size_t)s*64 + c]);
  if (c == 0) atomicAdd(&cnt[d], 1.f);
}
__global__ void k_pool_div(float* __restrict__ h2, const float* __restrict__ cnt, int N){
  int i = blockIdx.x*blockDim.x + threadIdx.x;
  if (i >= N*64) return;
  h2[i] = h2[i] / fmaxf(cnt[i >> 6], 1.f);
}

// ---------- fully fused set2set: one block per graph, 5 steps internally ----------
__global__ __launch_bounds__(256) void k_set2set(const float* __restrict__ x, const int* __restrict__ rb,
                          const float* __restrict__ wih0, const float* __restrict__ whh0,
                          const float* __restrict__ b0,
                          const float* __restrict__ wih1, const float* __restrict__ whh1,
                          const float* __restrict__ b1,
                          float* __restrict__ xout){
  int b = blockIdx.x, j = threadIdx.x;
  int w = j >> 6, lane = j & 63;
  __shared__ float qstar[128], h0[64], c0[64], h1[64], c1[64];
  __shared__ float gs[256], wmax[4], wsum[4], racc[4][64];
  if (j < 128) qstar[j] = 0.f;
  if (j < 64){ h0[j] = 0.f; c0[j] = 0.f; h1[j] = 0.f; c1[j] = 0.f; }
  __syncthreads();
  int n0 = rb[b], n1 = rb[b+1];
  for (int s = 0; s < 5; ++s){
    // LSTM0: 256 gate rows, input qstar[128], hidden h0[64]
    {
      float a0 = b0[j], a1 = 0.f, a2 = 0.f, a3 = 0.f;
      const float* wr = wih0 + (size_t)j*128;
      #pragma unroll 8
      for (int k = 0; k < 128; k += 4){
        a0 = fmaf(wr[k],   qstar[k],   a0);
        a1 = fmaf(wr[k+1], qstar[k+1], a1);
        a2 = fmaf(wr[k+2], qstar[k+2], a2);
        a3 = fmaf(wr[k+3], qstar[k+3], a3);
      }
      const float* w2 = whh0 + (size_t)j*64;
      #pragma unroll 8
      for (int k = 0; k < 64; k += 4){
        a0 = fmaf(w2[k],   h0[k],   a0);
        a1 = fmaf(w2[k+1], h0[k+1], a1);
        a2 = fmaf(w2[k+2], h0[k+2], a2);
        a3 = fmaf(w2[k+3], h0[k+3], a3);
      }
      gs[j] = (a0 + a1) + (a2 + a3);
    }
    __syncthreads();
    if (j < 64){
      float ig = sigf(gs[j]);
      float fg = sigf(gs[64+j]);
      float gg = tanhf(gs[128+j]);
      float og = sigf(gs[192+j]);
      float cn = fg*c0[j] + ig*gg;
      c0[j] = cn;
      h0[j] = og*tanhf(cn);
    }
    __syncthreads();
    // LSTM1: input h0 (new), hidden h1 (old)
    {
      float a0 = b1[j], a1 = 0.f, a2 = 0.f, a3 = 0.f;
      const float* wr = wih1 + (size_t)j*64;
      const float* w2 = whh1 + (size_t)j*64;
      #pragma unroll 8
      for (int k = 0; k < 64; k += 4){
        a0 = fmaf(wr[k],   h0[k],   a0);
        a1 = fmaf(wr[k+1], h0[k+1], a1);
        a2 = fmaf(wr[k+2], h0[k+2], a2);
        a3 = fmaf(wr[k+3], h0[k+3], a3);
      }
      #pragma unroll 8
      for (int k = 0; k < 64; k += 4){
        a0 = fmaf(w2[k],   h1[k],   a0);
        a1 = fmaf(w2[k+1], h1[k+1], a1);
        a2 = fmaf(w2[k+2], h1[k+2], a2);
        a3 = fmaf(w2[k+3], h1[k+3], a3);
      }
      gs[j] = (a0 + a1) + (a2 + a3);
    }
    __syncthreads();
    if (j < 64){
      float ig = sigf(gs[j]);
      float fg = sigf(gs[64+j]);
      float gg = tanhf(gs[128+j]);
      float og = sigf(gs[192+j]);
      float cn = fg*c1[j] + ig*gg;
      c1[j] = cn;
      float hn = og*tanhf(cn);
      h1[j] = hn;
      qstar[j] = hn;          // q half of q_star
    }
    __syncthreads();
    // attention over [n0,n1): softmax(x·q) then r = sum a*x
    float lmax = -3.4e38f;
    for (int n = n0 + w; n < n1; n += 4){
      float v = x[(size_t)n*64 + lane]*qstar[lane];
      #pragma unroll
      for (int o = 32; o; o >>= 1) v += __shfl_xor(v, o);
      lmax = fmaxf(lmax, v);
    }
    if (lane == 0) wmax[w] = lmax;
    __syncthreads();
    float bmax = fmaxf(fmaxf(wmax[0], wmax[1]), fmaxf(wmax[2], wmax[3]));
    float lsum = 0.f, lr = 0.f;
    for (int n = n0 + w; n < n1; n += 4){
      float xv = x[(size_t)n*64 + lane];
      float v = xv*qstar[lane];
      #pragma unroll
      for (int o = 32; o; o >>= 1) v += __shfl_xor(v, o);
      float wexp = expf(v - bmax);
      lsum += wexp;
      lr = fmaf(wexp, xv, lr);
    }
    if (lane == 0) wsum[w] = lsum;
    racc[w][lane] = lr;
    __syncthreads();
    if (j < 64){
      float r = racc[0][j] + racc[1][j] + racc[2][j] + racc[3][j];
      float denom = wsum[0] + wsum[1] + wsum[2] + wsum[3];
      qstar[64 + j] = (denom > 0.f) ? (r/denom) : 0.f;
    }
    __syncthreads();
  }
  if (j < 128) xout[(size_t)b*128 + j] = qstar[j];
}

// ---------- head ----------
__global__ void k_concat(const float* __restrict__ x1, const float* __restrict__ x2,
                         float* __restrict__ z){
  int i = blockIdx.x*blockDim.x + threadIdx.x;
  if (i >= 256*256) return;
  int b = i >> 8, c = i & 255;
  z[i] = (c < 128) ? x1[b*128 + c] : x2[b*128 + (c - 128)];
}
__global__ void k_bn_par(float* __restrict__ X, const float* __restrict__ g,
                         const float* __restrict__ b, int F, int relu){
  int f = blockIdx.x, i = threadIdx.x;
  float v = X[(size_t)i*F + f];
  __shared__ float s1[256], s2[256];
  s1[i] = v; s2[i] = v*v;
  __syncthreads();
  for (int o = 128; o; o >>= 1){
    if (i < o){ s1[i] += s1[i+o]; s2[i] += s2[i+o]; }
    __syncthreads();
  }
  float mean = s1[0]*(1.f/256.f);
  float var  = s2[0]*(1.f/256.f) - mean*mean;
  float y = (v - mean)*rsqrtf(var + 1e-5f)*g[f] + b[f];
  if (relu) y = fmaxf(y, 0.f);
  X[(size_t)i*F + f] = y;
}
__global__ void k_fc(const float* __restrict__ X, const float* __restrict__ W,
                     const float* __restrict__ bias, float* __restrict__ Y, int K, int F){
  int b = blockIdx.x, f = threadIdx.x;
  if (f >= F) return;
  const float* xr = X + (size_t)b*K;
  const float* wr = W + (size_t)f*K;
  float acc = bias[f];
  for (int k = 0; k < K; ++k) acc = fmaf(xr[k], wr[k], acc);
  Y[(size_t)b*F + f] = acc;
}
__global__ void k_fc_out(const float* __restrict__ z2, const float* __restrict__ w,
                         const float* __restrict__ bias, float* __restrict__ out){
  int b = blockIdx.x*blockDim.x + threadIdx.x;
  if (b >= 256) return;
  float acc = bias[0];
  #pragma unroll
  for (int k = 0; k < 64; ++k) acc = fmaf(z2[b*64 + k], w[k], acc);
  out[b] = acc;
}

extern "C" void kernel_launch(void* const* d_in, const int* in_sizes, int n_in,
                              void* d_out, int out_size, void* d_ws, size_t ws_size,
                              hipStream_t stream) {
  const float* x_in     = (const float*)d_in[0];
  const float* edge_attr= (const float*)d_in[1];
  const float* conv_w   = (const float*)d_in[2];
  const float* conv_wih = (const float*)d_in[3];
  const float* conv_whh = (const float*)d_in[4];
  const float* conv_bih = (const float*)d_in[5];
  const float* conv_bhh = (const float*)d_in[6];
  const float* conv_nt  = (const float*)d_in[7];
  const float* s1_wih0 = (const float*)d_in[8];
  const float* s1_whh0 = (const float*)d_in[9];
  const float* s1_b0   = (const float*)d_in[10];
  const float* s1_wih1 = (const float*)d_in[11];
  const float* s1_whh1 = (const float*)d_in[12];
  const float* s1_b1   = (const float*)d_in[13];
  const float* s2_wih0 = (const float*)d_in[14];
  const float* s2_whh0 = (const float*)d_in[15];
  const float* s2_b0   = (const float*)d_in[16];
  const float* s2_wih1 = (const float*)d_in[17];
  const float* s2_whh1 = (const float*)d_in[18];
  const float* s2_b1   = (const float*)d_in[19];
  const float* bn_g    = (const float*)d_in[20];
  const float* bn_b    = (const float*)d_in[21];
  const float* prebn_g = (const float*)d_in[22];
  const float* prebn_b = (const float*)d_in[23];
  const float* fc_w0   = (const float*)d_in[24];
  const float* fc_b0   = (const float*)d_in[25];
  const float* fc_w1   = (const float*)d_in[26];
  const float* fc_b1   = (const float*)d_in[27];
  const float* fc_w2   = (const float*)d_in[28];
  const float* fc_b2   = (const float*)d_in[29];
  const float* fcbn_g0 = (const float*)d_in[30];
  const float* fcbn_b0 = (const float*)d_in[31];
  const float* fcbn_g1 = (const float*)d_in[32];
  const float* fcbn_b1 = (const float*)d_in[33];
  const int* edge_index   = (const int*)d_in[34];
  const int* node_type    = (const int*)d_in[35];
  const int* batch        = (const int*)d_in[36];
  const int* assign_src   = (const int*)d_in[37];
  const int* assign_dst   = (const int*)d_in[38];
  const int* edge_index_2 = (const int*)d_in[39];
  const int* batch_2      = (const int*)d_in[40];
  (void)in_sizes; (void)n_in; (void)out_size;

  // ---- workspace layout ----
  float* Wp = (float*)d_ws;
  float *h, *tr, *aggr, *coeff, *h2, *cnt;
  float *x1, *x2, *z, *z1, *z2, *stats, *wihT, *whhT;
  int *etype, *cnt1, *R1, *ep1, *cnt2, *R2, *ep2, *csum, *rb1, *rb2;
  size_t o = 0;
  auto layout = [&](size_t trsize){
    o = 0;
    auto alloc = [&](size_t n){ float* p = Wp + o; o += n; return p; };
    h     = alloc((size_t)NN1*64);
    tr    = alloc(trsize);
    aggr  = alloc((size_t)NN1*64);
    coeff = alloc(NN1);
    h2    = alloc((size_t)NN2*64);
    cnt   = alloc(NN2);
    x1    = alloc(256*128);
    x2    = alloc(256*128);
    z     = alloc(256*256);
    z1    = alloc(256*128);
    z2    = alloc(256*64);
    stats = alloc(128);
    wihT  = alloc(5*12288);
    whhT  = alloc(5*12288);
    etype = (int*)alloc(EE1);
    cnt1  = (int*)alloc(4*NN1);
    R1    = (int*)alloc(4*NN1 + 1);
    ep1   = (int*)alloc(EE1);
    cnt2  = (int*)alloc(NN2);
    R2    = (int*)alloc(NN2 + 1);
    ep2   = (int*)alloc(EE2);
    csum  = (int*)alloc(260);
    rb1   = (int*)alloc(257);
    rb2   = (int*)alloc(257);
  };
  layout((size_t)6*NN1*64);
  int bigpath = (o*sizeof(float) <= ws_size);
  if (!bigpath) layout((size_t)NN1*64);

  const int* src1 = edge_index;
  const int* dst1 = edge_index + EE1;
  const int* src2 = edge_index_2;
  const int* dst2 = edge_index_2 + EE2;

  k_etype<<<(EE1+255)/256, 256, 0, stream>>>(edge_attr, etype, EE1);
  k_copy<<<(NN1*64+255)/256, 256, 0, stream>>>(x_in, h, NN1*64);
  k_wtrans<<<(5*12288+255)/256, 256, 0, stream>>>(conv_wih, conv_whh, wihT, whhT);
  k_batchptr<<<(NN1+255)/256, 256, 0, stream>>>(batch, rb1, NN1, 256);
  k_batchptr<<<(NN2+255)/256, 256, 0, stream>>>(batch_2, rb2, NN2, 256);

  {  // level-1 CSR
    int M = bigpath ? NN1 : 4*NN1;
    int nchunk = (M + 1023)/1024;
    hipMemsetAsync(cnt1, 0, (size_t)M*sizeof(int), stream);
    k_hist<<<(EE1+255)/256, 256, 0, stream>>>(dst1, etype, cnt1, EE1, NN1, !bigpath);
    k_chunksum<<<nchunk, 256, 0, stream>>>(cnt1, csum, M);
    k_chunkscan<<<1, 256, 0, stream>>>(csum, nchunk);
    k_chunkapply<<<nchunk, 256, 0, stream>>>(cnt1, csum, R1, cnt1, M);
    k_scatter<<<(EE1+255)/256, 256, 0, stream>>>(src1, dst1, etype, cnt1, ep1, EE1, NN1, !bigpath);
  }
  {  // level-2 CSR
    int M = NN2, nchunk = (M + 1023)/1024;
    hipMemsetAsync(cnt2, 0, (size_t)M*sizeof(int), stream);
    k_hist<<<(EE2+255)/256, 256, 0, stream>>>(dst2, nullptr, cnt2, EE2, NN2, 0);
    k_chunksum<<<nchunk, 256, 0, stream>>>(cnt2, csum, M);
    k_chunkscan<<<1, 256, 0, stream>>>(csum, nchunk);
    k_chunkapply<<<nchunk, 256, 0, stream>>>(cnt2, csum, R2, cnt2, M);
    k_scatter<<<(EE2+255)/256, 256, 0, stream>>>(src2, dst2, nullptr, cnt2, ep2, EE2, NN2, 0);
  }

  auto gru = [&](float* hbuf, int N, int lidx){
    if (bigpath){
      k_gru_gemm<<<6*1024, 256, 0, stream>>>(aggr, hbuf,
          wihT + (size_t)lidx*12288, whhT + (size_t)lidx*12288, tr, N);
      k_gru_fin<<<(N*16+255)/256, 256, 0, stream>>>(tr, conv_bih + lidx*192, conv_bhh + lidx*192, hbuf, N);
    } else {
      k_gru_old<<<1024, 192, 0, stream>>>(aggr, hbuf,
          conv_wih + (size_t)lidx*12288, conv_whh + (size_t)lidx*12288,
          conv_bih + lidx*192, conv_bhh + lidx*192, N);
    }
  };

  // ---- level-1: 3x MGGC(L=3) + BN + ReLU ----
  for (int i = 0; i < 3; ++i){
    k_coeff<<<(NN1+255)/256, 256, 0, stream>>>(conv_nt + i*9, node_type, coeff, NN1);
    for (int l = 0; l < 3; ++l){
      const float* Wl = conv_w + (size_t)(i*3+l)*4*4096;
      if (bigpath){
        k_transform4<<<4096, 256, 0, stream>>>(h, Wl, coeff, tr, NN1);
        k_sweep_p<<<(NN1+3)/4, 256, 0, stream>>>(tr, R1, ep1, aggr, NN1);
      } else {
        for (int t = 0; t < 4; ++t){
          k_transform4<<<1024, 256, 0, stream>>>(h, Wl + (size_t)t*4096, coeff, tr, NN1);
          k_sweep<<<(NN1+3)/4, 256, 0, stream>>>(tr, R1 + (size_t)t*NN1, ep1, aggr, NN1, t == 0);
        }
      }
      gru(h, NN1, i);
    }
    hipMemsetAsync(stats, 0, 128*sizeof(float), stream);
    k_bnstats<<<256, 256, 0, stream>>>(h, stats, NN1);
    k_bnapply<<<(NN1*64+255)/256, 256, 0, stream>>>(h, stats, bn_g + i*64, bn_b + i*64, NN1, 1);
  }

  // ---- set2set (single fused kernel) ----
  k_set2set<<<256, 256, 0, stream>>>(h, rb1, s1_wih0, s1_whh0, s1_b0, s1_wih1, s1_whh1, s1_b1, x1);

  // ---- avg_pool ----
  hipMemsetAsync(h2, 0, (size_t)NN2*64*sizeof(float), stream);
  hipMemsetAsync(cnt, 0, (size_t)NN2*sizeof(float), stream);
  k_pool_acc<<<(AA*64+255)/256, 256, 0, stream>>>(h, assign_src, assign_dst, h2, cnt, AA);
  k_pool_div<<<(NN2*64+255)/256, 256, 0, stream>>>(h2, cnt, NN2);

  // ---- level-2: 2x relu(MGGC(L=3)) ----
  for (int L = 3; L < 5; ++L){
    for (int l = 0; l < 3; ++l){
      k_transform4<<<1024, 256, 0, stream>>>(h2, conv_w + (size_t)(L*3+l)*4*4096, nullptr, tr, NN2);
      k_sweep_p<<<(NN2+3)/4, 256, 0, stream>>>(tr, R2, ep2, aggr, NN2);
      gru(h2, NN2, L);
    }
    k_relu<<<(NN2*64+255)/256, 256, 0, stream>>>(h2, NN2*64);
  }

  k_set2set<<<256, 256, 0, stream>>>(h2, rb2, s2_wih0, s2_whh0, s2_b0, s2_wih1, s2_whh1, s2_b1, x2);

  // ---- head ----
  k_concat<<<256, 256, 0, stream>>>(x1, x2, z);
  k_bn_par<<<256, 256, 0, stream>>>(z, prebn_g, prebn_b, 256, 0);
  k_fc<<<256, 128, 0, stream>>>(z, fc_w0, fc_b0, z1, 256, 128);
  k_bn_par<<<128, 256, 0, stream>>>(z1, fcbn_g0, fcbn_b0, 128, 1);
  k_fc<<<256, 64, 0, stream>>>(z1, fc_w1, fc_b1, z2, 128, 64);
  k_bn_par<<<64, 256, 0, stream>>>(z2, fcbn_g1, fcbn_b1, 64, 1);
  k_fc_out<<<4, 64, 0, stream>>>(z2, fc_w2, fc_b2, (float*)d_out);
}

// Round 10
// 4961.911 us; speedup vs baseline: 1.9537x; 1.9537x over previous
//
#include <hip/hip_runtime.h>

#define NN1 60000
#define EE1 600000
#define NN2 20000
#define EE2 150000
#define AA  60000

__device__ __forceinline__ float sigf(float x){ return 1.f/(1.f+expf(-x)); }

// ---------- elementwise ----------
__global__ void k_relu(float* a, int n){
  int i = blockIdx.x*blockDim.x + threadIdx.x;
  if (i < n) a[i] = fmaxf(a[i], 0.f);
}
__global__ void k_copy(const float* __restrict__ a, float* __restrict__ o, int n){
  int i = blockIdx.x*blockDim.x + threadIdx.x;
  if (i < n) o[i] = a[i];
}

// ---------- edge type ----------
__global__ void k_etype(const float* __restrict__ ea, int* __restrict__ etype, int E){
  int e = blockIdx.x*blockDim.x + threadIdx.x;
  if (e >= E) return;
  const float* p = ea + (size_t)e*10;
  float best = p[0]; int bi = 0;
  #pragma unroll
  for (int k = 1; k < 4; ++k){ float v = p[k]; if (v > best){ best = v; bi = k; } }
  etype[e] = bi;
}

__global__ void k_coeff(const float* __restrict__ nt, const int* __restrict__ node_type,
                        float* __restrict__ coeff, int N){
  int n = blockIdx.x*blockDim.x + threadIdx.x;
  if (n < N) coeff[n] = nt[node_type[n]];
}

// ---------- batch row pointers (batch sorted ascending) ----------
__global__ void k_batchptr(const int* __restrict__ batch, int* __restrict__ rb, int N, int B){
  int n = blockIdx.x*blockDim.x + threadIdx.x;
  if (n >= N) return;
  int b = batch[n];
  if (n == 0){ for (int g = 0; g <= b; ++g) rb[g] = 0; }
  else {
    int pb = batch[n-1];
    for (int g = pb+1; g <= b; ++g) rb[g] = n;
  }
  if (n == N-1){ for (int g = b+1; g <= B; ++g) rb[g] = N; }
}

// ---------- GRU weight transpose: wih[l][j][c] -> wihT[l][t][c][d], j=64t+d ----------
__global__ void k_wtrans(const float* __restrict__ wih, const float* __restrict__ whh,
                         float* __restrict__ wihT, float* __restrict__ whhT){
  int idx = blockIdx.x*256 + threadIdx.x;   // 5*192*64 = 61440
  if (idx >= 5*192*64) return;
  int l = idx / 12288, r = idx % 12288;
  int j = r >> 6, c = r & 63;
  int t = j >> 6, d = j & 63;
  int dst = l*12288 + t*4096 + c*64 + d;
  wihT[dst] = wih[idx];
  whhT[dst] = whh[idx];
}

// ---------- CSR build ----------
__global__ void k_hist(const int* __restrict__ dst, const int* __restrict__ etype,
                       int* __restrict__ cnt, int E, int N, int tkey){
  int e = blockIdx.x*blockDim.x + threadIdx.x;
  if (e >= E) return;
  int t = etype ? etype[e] : 0;
  int key = tkey ? (t*N + dst[e]) : dst[e];
  atomicAdd(&cnt[key], 1);
}
__global__ void k_chunksum(const int* __restrict__ cnt, int* __restrict__ csum, int M){
  __shared__ int sh[256];
  int base = blockIdx.x*1024;
  int s = 0;
  for (int i = threadIdx.x; i < 1024; i += 256){
    int idx = base + i;
    if (idx < M) s += cnt[idx];
  }
  sh[threadIdx.x] = s;
  __syncthreads();
  for (int o = 128; o; o >>= 1){
    if (threadIdx.x < o) sh[threadIdx.x] += sh[threadIdx.x + o];
    __syncthreads();
  }
  if (threadIdx.x == 0) csum[blockIdx.x] = sh[0];
}
__global__ void k_chunkscan(int* __restrict__ csum, int nchunk){
  __shared__ int sh[256];
  int i = threadIdx.x;
  int v = (i < nchunk) ? csum[i] : 0;
  sh[i] = v; __syncthreads();
  for (int o = 1; o < 256; o <<= 1){
    int y = (i >= o) ? sh[i-o] : 0;
    __syncthreads();
    sh[i] += y;
    __syncthreads();
  }
  if (i < nchunk) csum[i] = sh[i] - v;
  if (i == 255) csum[nchunk] = sh[255];
}
__global__ void k_chunkapply(const int* __restrict__ cnt, const int* __restrict__ csum,
                             int* __restrict__ R, int* __restrict__ cur, int M){
  __shared__ int sh[256];
  int base = blockIdx.x*1024;
  int i0 = base + threadIdx.x*4;
  int v[4]; int s = 0;
  #pragma unroll
  for (int k = 0; k < 4; ++k){ int idx = i0 + k; v[k] = (idx < M) ? cnt[idx] : 0; s += v[k]; }
  sh[threadIdx.x] = s; __syncthreads();
  for (int o = 1; o < 256; o <<= 1){
    int y = (threadIdx.x >= o) ? sh[threadIdx.x-o] : 0;
    __syncthreads();
    sh[threadIdx.x] += y;
    __syncthreads();
  }
  int run = csum[blockIdx.x] + sh[threadIdx.x] - s;
  #pragma unroll
  for (int k = 0; k < 4; ++k){
    int idx = i0 + k;
    if (idx < M){ R[idx] = run; cur[idx] = run; run += v[k]; }
  }
  if (threadIdx.x == 255 && base + 1024 >= M) R[M] = csum[blockIdx.x] + sh[255];
}
__global__ void k_scatter(const int* __restrict__ src, const int* __restrict__ dst,
                          const int* __restrict__ etype, int* __restrict__ cur,
                          int* __restrict__ ep, int E, int N, int tkey){
  int e = blockIdx.x*blockDim.x + threadIdx.x;
  if (e >= E) return;
  int t = etype ? etype[e] : 0;
  int key = tkey ? (t*N + dst[e]) : dst[e];
  int pos = atomicAdd(&cur[key], 1);
  ep[pos] = (t << 20) | src[e];
}

// ---------- transform: tr[t][n][d] = coeff[n] * sum_c X[n][c]*W[t][c][d] ----------
// 4 independent accumulators; grid = T*1024 blocks
__global__ void k_transform4(const float* __restrict__ h, const float* __restrict__ W,
                             const float* __restrict__ coeff, float* __restrict__ tr, int N){
  int t = blockIdx.x >> 10, blk = blockIdx.x & 1023;
  int d = threadIdx.x & 63, sub = threadIdx.x >> 6;
  float wreg[64];
  const float* Wt = W + (size_t)t*4096;
  #pragma unroll
  for (int c = 0; c < 64; ++c) wreg[c] = Wt[c*64 + d];
  for (int n = blk*4 + sub; n < N; n += 4096){
    const float4* hr = (const float4*)(h + (size_t)n*64);
    float a0 = 0.f, a1 = 0.f, a2 = 0.f, a3 = 0.f;
    #pragma unroll
    for (int c = 0; c < 16; ++c){
      float4 v = hr[c];
      a0 = fmaf(v.x, wreg[4*c+0], a0);
      a1 = fmaf(v.y, wreg[4*c+1], a1);
      a2 = fmaf(v.z, wreg[4*c+2], a2);
      a3 = fmaf(v.w, wreg[4*c+3], a3);
    }
    float acc = (a0 + a1) + (a2 + a3);
    if (coeff) acc *= coeff[n];
    tr[((size_t)t*N + n)*64 + d] = acc;
  }
}

// ---------- merged sweep ----------
__global__ void k_sweep_p(const float* __restrict__ tr, const int* __restrict__ R,
                          const int* __restrict__ ep, float* __restrict__ aggr, int N){
  int w = threadIdx.x >> 6, lane = threadIdx.x & 63;
  int d = blockIdx.x*4 + w;
  if (d >= N) return;
  int p = R[d], pend = R[d+1];
  float acc = 0.f;
  while (p < pend){
    int m = pend - p; if (m > 64) m = 64;
    int ev = (lane < m) ? ep[p + lane] : 0;
    for (int j = 0; j < m; ++j){
      int pk = __shfl(ev, j);
      int s = pk & 0xFFFFF, t = pk >> 20;
      acc += tr[((size_t)t*N + s)*64 + lane];
    }
    p += m;
  }
  aggr[(size_t)d*64 + lane] = acc;
}
__global__ void k_sweep(const float* __restrict__ tr, const int* __restrict__ R,
                        const int* __restrict__ ep, float* __restrict__ aggr,
                        int N, int first){
  int w = threadIdx.x >> 6, lane = threadIdx.x & 63;
  int d = blockIdx.x*4 + w;
  if (d >= N) return;
  int p = R[d], pend = R[d+1];
  float acc = first ? 0.f : aggr[(size_t)d*64 + lane];
  while (p < pend){
    int m = pend - p; if (m > 64) m = 64;
    int ev = (lane < m) ? ep[p + lane] : 0;
    for (int j = 0; j < m; ++j){
      int s = __shfl(ev, j) & 0xFFFFF;
      acc += tr[(size_t)s*64 + lane];
    }
    p += m;
  }
  aggr[(size_t)d*64 + lane] = acc;
}

// ---------- GRU finalize: gb = [gi_r, gi_z, gi_n, gh_r, gh_z, gh_n] slabs of [N][64] ----------
__global__ void k_gru_fin(const float* __restrict__ gb,
                          const float* __restrict__ bih, const float* __restrict__ bhh,
                          float* __restrict__ h, int N){
  int i = blockIdx.x*256 + threadIdx.x;     // over N*16 float4 slots
  if (i >= N*16) return;
  int q = i & 15;
  const float4* g4 = (const float4*)gb;
  size_t S = (size_t)N*16;
  float4 gi0 = g4[i], gi1 = g4[S + i], gi2 = g4[2*S + i];
  float4 gh0 = g4[3*S + i], gh1 = g4[4*S + i], gh2 = g4[5*S + i];
  const float4* bi4 = (const float4*)bih;
  const float4* bh4 = (const float4*)bhh;
  float4 bir = bi4[q],    bhr = bh4[q];
  float4 biz = bi4[16+q], bhz = bh4[16+q];
  float4 bin = bi4[32+q], bhn = bh4[32+q];
  float4* h4 = (float4*)h;
  float4 hv = h4[i];
  float4 out;
  {
    float r = sigf(gi0.x + gh0.x + bir.x + bhr.x);
    float z = sigf(gi1.x + gh1.x + biz.x + bhz.x);
    float nn = tanhf(gi2.x + bin.x + r*(gh2.x + bhn.x));
    out.x = (1.f - z)*nn + z*hv.x;
  }
  {
    float r = sigf(gi0.y + gh0.y + bir.y + bhr.y);
    float z = sigf(gi1.y + gh1.y + biz.y + bhz.y);
    float nn = tanhf(gi2.y + bin.y + r*(gh2.y + bhn.y));
    out.y = (1.f - z)*nn + z*hv.y;
  }
  {
    float r = sigf(gi0.z + gh0.z + bir.z + bhr.z);
    float z = sigf(gi1.z + gh1.z + biz.z + bhz.z);
    float nn = tanhf(gi2.z + bin.z + r*(gh2.z + bhn.z));
    out.z = (1.f - z)*nn + z*hv.z;
  }
  {
    float r = sigf(gi0.w + gh0.w + bir.w + bhr.w);
    float z = sigf(gi1.w + gh1.w + biz.w + bhz.w);
    float nn = tanhf(gi2.w + bin.w + r*(gh2.w + bhn.w));
    out.w = (1.f - z)*nn + z*hv.w;
  }
  h4[i] = out;
}

// ---------- GRU fallback ----------
__global__ void k_gru_old(const float* __restrict__ aggr, float* __restrict__ h,
                      const float* __restrict__ wih, const float* __restrict__ whh,
                      const float* __restrict__ bih, const float* __restrict__ bhh, int N){
  int j = threadIdx.x;
  float4 wi4[16], wh4[16];
  const float4* wisrc = (const float4*)(wih + (size_t)j*64);
  const float4* whsrc = (const float4*)(whh + (size_t)j*64);
  #pragma unroll
  for (int c = 0; c < 16; ++c){ wi4[c] = wisrc[c]; wh4[c] = whsrc[c]; }
  float bi = bih[j], bh = bhh[j];
  __shared__ float gi_s[192], gh_s[192];
  for (int n = blockIdx.x; n < N; n += gridDim.x){
    const float4* mr = (const float4*)(aggr + (size_t)n*64);
    const float4* hr = (const float4*)(h + (size_t)n*64);
    float ai = bi, ah = bh;
    #pragma unroll
    for (int c = 0; c < 16; ++c){
      float4 m4 = mr[c], h4 = hr[c];
      ai = fmaf(m4.x, wi4[c].x, ai); ah = fmaf(h4.x, wh4[c].x, ah);
      ai = fmaf(m4.y, wi4[c].y, ai); ah = fmaf(h4.y, wh4[c].y, ah);
      ai = fmaf(m4.z, wi4[c].z, ai); ah = fmaf(h4.z, wh4[c].z, ah);
      ai = fmaf(m4.w, wi4[c].w, ai); ah = fmaf(h4.w, wh4[c].w, ah);
    }
    gi_s[j] = ai; gh_s[j] = ah;
    __syncthreads();
    if (j < 64){
      float r  = sigf(gi_s[j]      + gh_s[j]);
      float z  = sigf(gi_s[64+j]   + gh_s[64+j]);
      float nn = tanhf(gi_s[128+j] + r*gh_s[128+j]);
      h[(size_t)n*64 + j] = (1.f - z)*nn + z*h[(size_t)n*64 + j];
    }
    __syncthreads();
  }
}

// ---------- batch norm over nodes ----------
__global__ void k_bnstats(const float* __restrict__ h, float* __restrict__ stats, int N){
  int c = threadIdx.x & 63;
  int g = threadIdx.x >> 6;
  float s = 0.f, s2 = 0.f;
  for (int n = blockIdx.x*4 + g; n < N; n += gridDim.x*4){
    float v = h[(size_t)n*64 + c]; s += v; s2 += v*v;
  }
  __shared__ float sh[4][64], sh2[4][64];
  sh[g][c] = s; sh2[g][c] = s2;
  __syncthreads();
  if (g == 0){
    float ts = sh[0][c]+sh[1][c]+sh[2][c]+sh[3][c];
    float t2 = sh2[0][c]+sh2[1][c]+sh2[2][c]+sh2[3][c];
    atomicAdd(&stats[c], ts); atomicAdd(&stats[64+c], t2);
  }
}
__global__ void k_bnapply(float* __restrict__ h, const float* __restrict__ stats,
                          const float* __restrict__ g, const float* __restrict__ b,
                          int N, int relu){
  int i = blockIdx.x*blockDim.x + threadIdx.x;
  if (i >= N*64) return;
  int c = i & 63;
  float inv = 1.f/(float)N;
  float mean = stats[c]*inv;
  float var  = stats[64+c]*inv - mean*mean;
  float y = (h[i]-mean)*rsqrtf(var + 1e-5f)*g[c] + b[c];
  if (relu) y = fmaxf(y, 0.f);
  h[i] = y;
}

// ---------- avg_pool ----------
__global__ void k_pool_acc(const float* __restrict__ h, const int* __restrict__ asrc,
                           const int* __restrict__ adst, float* __restrict__ h2,
                           float* __restrict__ cnt, int A){
  int i = blockIdx.x*blockDim.x + threadIdx.x;
  if (i >= A*64) return;
  int a = i >> 6, c = i & 63;
  int s = asrc[a], d = adst[a];
  atomicAdd(&h2[(size_t)d*64 + c], h[(size_t)s*64 + c]);
  if (c == 0) atomicAdd(&cnt[d], 1.f);
}
__global__ void k_pool_div(float* __restrict__ h2, const float* __restrict__ cnt, int N){
  int i = blockIdx.x*blockDim.x + threadIdx.x;
  if (i >= N*64) return;
  h2[i] = h2[i] / fmaxf(cnt[i >> 6], 1.f);
}

// ---------- fully fused set2set: one block per graph, 5 steps internally ----------
__global__ __launch_bounds__(256) void k_set2set(const float* __restrict__ x, const int* __restrict__ rb,
                          const float* __restrict__ wih0, const float* __restrict__ whh0,
                          const float* __restrict__ b0,
                          const float* __restrict__ wih1, const float* __restrict__ whh1,
                          const float* __restrict__ b1,
                          float* __restrict__ xout){
  int b = blockIdx.x, j = threadIdx.x;
  int w = j >> 6, lane = j & 63;
  __shared__ float qstar[128], h0[64], c0[64], h1[64], c1[64];
  __shared__ float gs[256], wmax[4], wsum[4], racc[4][64];
  if (j < 128) qstar[j] = 0.f;
  if (j < 64){ h0[j] = 0.f; c0[j] = 0.f; h1[j] = 0.f; c1[j] = 0.f; }
  __syncthreads();
  int n0 = rb[b], n1 = rb[b+1];
  for (int s = 0; s < 5; ++s){
    // LSTM0: 256 gate rows, input qstar[128], hidden h0[64]
    {
      float a0 = b0[j], a1 = 0.f, a2 = 0.f, a3 = 0.f;
      const float* wr = wih0 + (size_t)j*128;
      #pragma unroll 8
      for (int k = 0; k < 128; k += 4){
        a0 = fmaf(wr[k],   qstar[k],   a0);
        a1 = fmaf(wr[k+1], qstar[k+1], a1);
        a2 = fmaf(wr[k+2], qstar[k+2], a2);
        a3 = fmaf(wr[k+3], qstar[k+3], a3);
      }
      const float* w2 = whh0 + (size_t)j*64;
      #pragma unroll 8
      for (int k = 0; k < 64; k += 4){
        a0 = fmaf(w2[k],   h0[k],   a0);
        a1 = fmaf(w2[k+1], h0[k+1], a1);
        a2 = fmaf(w2[k+2], h0[k+2], a2);
        a3 = fmaf(w2[k+3], h0[k+3], a3);
      }
      gs[j] = (a0 + a1) + (a2 + a3);
    }
    __syncthreads();
    if (j < 64){
      float ig = sigf(gs[j]);
      float fg = sigf(gs[64+j]);
      float gg = tanhf(gs[128+j]);
      float og = sigf(gs[192+j]);
      float cn = fg*c0[j] + ig*gg;
      c0[j] = cn;
      h0[j] = og*tanhf(cn);
    }
    __syncthreads();
    // LSTM1: input h0 (new), hidden h1 (old)
    {
      float a0 = b1[j], a1 = 0.f, a2 = 0.f, a3 = 0.f;
      const float* wr = wih1 + (size_t)j*64;
      const float* w2 = whh1 + (size_t)j*64;
      #pragma unroll 8
      for (int k = 0; k < 64; k += 4){
        a0 = fmaf(wr[k],   h0[k],   a0);
        a1 = fmaf(wr[k+1], h0[k+1], a1);
        a2 = fmaf(wr[k+2], h0[k+2], a2);
        a3 = fmaf(wr[k+3], h0[k+3], a3);
      }
      #pragma unroll 8
      for (int k = 0; k < 64; k += 4){
        a0 = fmaf(w2[k],   h1[k],   a0);
        a1 = fmaf(w2[k+1], h1[k+1], a1);
        a2 = fmaf(w2[k+2], h1[k+2], a2);
        a3 = fmaf(w2[k+3], h1[k+3], a3);
      }
      gs[j] = (a0 + a1) + (a2 + a3);
    }
    __syncthreads();
    if (j < 64){
      float ig = sigf(gs[j]);
      float fg = sigf(gs[64+j]);
      float gg = tanhf(gs[128+j]);
      float og = sigf(gs[192+j]);
      float cn = fg*c1[j] + ig*gg;
      c1[j] = cn;
      float hn = og*tanhf(cn);
      h1[j] = hn;
      qstar[j] = hn;          // q half of q_star
    }
    __syncthreads();
    // attention over [n0,n1): softmax(x·q) then r = sum a*x
    float lmax = -3.4e38f;
    for (int n = n0 + w; n < n1; n += 4){
      float v = x[(size_t)n*64 + lane]*qstar[lane];
      #pragma unroll
      for (int o = 32; o; o >>= 1) v += __shfl_xor(v, o);
      lmax = fmaxf(lmax, v);
    }
    if (lane == 0) wmax[w] = lmax;
    __syncthreads();
    float bmax = fmaxf(fmaxf(wmax[0], wmax[1]), fmaxf(wmax[2], wmax[3]));
    float lsum = 0.f, lr = 0.f;
    for (int n = n0 + w; n < n1; n += 4){
      float xv = x[(size_t)n*64 + lane];
      float v = xv*qstar[lane];
      #pragma unroll
      for (int o = 32; o; o >>= 1) v += __shfl_xor(v, o);
      float wexp = expf(v - bmax);
      lsum += wexp;
      lr = fmaf(wexp, xv, lr);
    }
    if (lane == 0) wsum[w] = lsum;
    racc[w][lane] = lr;
    __syncthreads();
    if (j < 64){
      float r = racc[0][j] + racc[1][j] + racc[2][j] + racc[3][j];
      float denom = wsum[0] + wsum[1] + wsum[2] + wsum[3];
      qstar[64 + j] = (denom > 0.f) ? (r/denom) : 0.f;
    }
    __syncthreads();
  }
  if (j < 128) xout[(size_t)b*128 + j] = qstar[j];
}

// ---------- head ----------
__global__ void k_concat(const float* __restrict__ x1, const float* __restrict__ x2,
                         float* __restrict__ z){
  int i = blockIdx.x*blockDim.x + threadIdx.x;
  if (i >= 256*256) return;
  int b = i >> 8, c = i & 255;
  z[i] = (c < 128) ? x1[b*128 + c] : x2[b*128 + (c - 128)];
}
__global__ void k_bn_par(float* __restrict__ X, const float* __restrict__ g,
                         const float* __restrict__ b, int F, int relu){
  int f = blockIdx.x, i = threadIdx.x;
  float v = X[(size_t)i*F + f];
  __shared__ float s1[256], s2[256];
  s1[i] = v; s2[i] = v*v;
  __syncthreads();
  for (int o = 128; o; o >>= 1){
    if (i < o){ s1[i] += s1[i+o]; s2[i] += s2[i+o]; }
    __syncthreads();
  }
  float mean = s1[0]*(1.f/256.f);
  float var  = s2[0]*(1.f/256.f) - mean*mean;
  float y = (v - mean)*rsqrtf(var + 1e-5f)*g[f] + b[f];
  if (relu) y = fmaxf(y, 0.f);
  X[(size_t)i*F + f] = y;
}
__global__ void k_fc(const float* __restrict__ X, const float* __restrict__ W,
                     const float* __restrict__ bias, float* __restrict__ Y, int K, int F){
  int b = blockIdx.x, f = threadIdx.x;
  if (f >= F) return;
  const float* xr = X + (size_t)b*K;
  const float* wr = W + (size_t)f*K;
  float acc = bias[f];
  for (int k = 0; k < K; ++k) acc = fmaf(xr[k], wr[k], acc);
  Y[(size_t)b*F + f] = acc;
}
__global__ void k_fc_out(const float* __restrict__ z2, const float* __restrict__ w,
                         const float* __restrict__ bias, float* __restrict__ out){
  int b = blockIdx.x*blockDim.x + threadIdx.x;
  if (b >= 256) return;
  float acc = bias[0];
  #pragma unroll
  for (int k = 0; k < 64; ++k) acc = fmaf(z2[b*64 + k], w[k], acc);
  out[b] = acc;
}

extern "C" void kernel_launch(void* const* d_in, const int* in_sizes, int n_in,
                              void* d_out, int out_size, void* d_ws, size_t ws_size,
                              hipStream_t stream) {
  const float* x_in     = (const float*)d_in[0];
  const float* edge_attr= (const float*)d_in[1];
  const float* conv_w   = (const float*)d_in[2];
  const float* conv_wih = (const float*)d_in[3];
  const float* conv_whh = (const float*)d_in[4];
  const float* conv_bih = (const float*)d_in[5];
  const float* conv_bhh = (const float*)d_in[6];
  const float* conv_nt  = (const float*)d_in[7];
  const float* s1_wih0 = (const float*)d_in[8];
  const float* s1_whh0 = (const float*)d_in[9];
  const float* s1_b0   = (const float*)d_in[10];
  const float* s1_wih1 = (const float*)d_in[11];
  const float* s1_whh1 = (const float*)d_in[12];
  const float* s1_b1   = (const float*)d_in[13];
  const float* s2_wih0 = (const float*)d_in[14];
  const float* s2_whh0 = (const float*)d_in[15];
  const float* s2_b0   = (const float*)d_in[16];
  const float* s2_wih1 = (const float*)d_in[17];
  const float* s2_whh1 = (const float*)d_in[18];
  const float* s2_b1   = (const float*)d_in[19];
  const float* bn_g    = (const float*)d_in[20];
  const float* bn_b    = (const float*)d_in[21];
  const float* prebn_g = (const float*)d_in[22];
  const float* prebn_b = (const float*)d_in[23];
  const float* fc_w0   = (const float*)d_in[24];
  const float* fc_b0   = (const float*)d_in[25];
  const float* fc_w1   = (const float*)d_in[26];
  const float* fc_b1   = (const float*)d_in[27];
  const float* fc_w2   = (const float*)d_in[28];
  const float* fc_b2   = (const float*)d_in[29];
  const float* fcbn_g0 = (const float*)d_in[30];
  const float* fcbn_b0 = (const float*)d_in[31];
  const float* fcbn_g1 = (const float*)d_in[32];
  const float* fcbn_b1 = (const float*)d_in[33];
  const int* edge_index   = (const int*)d_in[34];
  const int* node_type    = (const int*)d_in[35];
  const int* batch        = (const int*)d_in[36];
  const int* assign_src   = (const int*)d_in[37];
  const int* assign_dst   = (const int*)d_in[38];
  const int* edge_index_2 = (const int*)d_in[39];
  const int* batch_2      = (const int*)d_in[40];
  (void)in_sizes; (void)n_in; (void)out_size;

  // ---- workspace layout ----
  float* Wp = (float*)d_ws;
  float *h, *tr, *aggr, *coeff, *h2, *cnt;
  float *x1, *x2, *z, *z1, *z2, *stats, *wihT, *whhT;
  int *etype, *cnt1, *R1, *ep1, *cnt2, *R2, *ep2, *csum, *rb1, *rb2;
  size_t o = 0;
  auto layout = [&](size_t trsize){
    o = 0;
    auto alloc = [&](size_t n){ float* p = Wp + o; o += n; return p; };
    h     = alloc((size_t)NN1*64);
    tr    = alloc(trsize);
    aggr  = alloc((size_t)NN1*64);
    coeff = alloc(NN1);
    h2    = alloc((size_t)NN2*64);
    cnt   = alloc(NN2);
    x1    = alloc(256*128);
    x2    = alloc(256*128);
    z     = alloc(256*256);
    z1    = alloc(256*128);
    z2    = alloc(256*64);
    stats = alloc(128);
    wihT  = alloc(5*12288);
    whhT  = alloc(5*12288);
    etype = (int*)alloc(EE1);
    cnt1  = (int*)alloc(4*NN1);
    R1    = (int*)alloc(4*NN1 + 1);
    ep1   = (int*)alloc(EE1);
    cnt2  = (int*)alloc(NN2);
    R2    = (int*)alloc(NN2 + 1);
    ep2   = (int*)alloc(EE2);
    csum  = (int*)alloc(260);
    rb1   = (int*)alloc(257);
    rb2   = (int*)alloc(257);
  };
  layout((size_t)6*NN1*64);
  int bigpath = (o*sizeof(float) <= ws_size);
  if (!bigpath) layout((size_t)NN1*64);

  const int* src1 = edge_index;
  const int* dst1 = edge_index + EE1;
  const int* src2 = edge_index_2;
  const int* dst2 = edge_index_2 + EE2;

  k_etype<<<(EE1+255)/256, 256, 0, stream>>>(edge_attr, etype, EE1);
  k_copy<<<(NN1*64+255)/256, 256, 0, stream>>>(x_in, h, NN1*64);
  k_wtrans<<<(5*12288+255)/256, 256, 0, stream>>>(conv_wih, conv_whh, wihT, whhT);
  k_batchptr<<<(NN1+255)/256, 256, 0, stream>>>(batch, rb1, NN1, 256);
  k_batchptr<<<(NN2+255)/256, 256, 0, stream>>>(batch_2, rb2, NN2, 256);

  {  // level-1 CSR
    int M = bigpath ? NN1 : 4*NN1;
    int nchunk = (M + 1023)/1024;
    hipMemsetAsync(cnt1, 0, (size_t)M*sizeof(int), stream);
    k_hist<<<(EE1+255)/256, 256, 0, stream>>>(dst1, etype, cnt1, EE1, NN1, !bigpath);
    k_chunksum<<<nchunk, 256, 0, stream>>>(cnt1, csum, M);
    k_chunkscan<<<1, 256, 0, stream>>>(csum, nchunk);
    k_chunkapply<<<nchunk, 256, 0, stream>>>(cnt1, csum, R1, cnt1, M);
    k_scatter<<<(EE1+255)/256, 256, 0, stream>>>(src1, dst1, etype, cnt1, ep1, EE1, NN1, !bigpath);
  }
  {  // level-2 CSR
    int M = NN2, nchunk = (M + 1023)/1024;
    hipMemsetAsync(cnt2, 0, (size_t)M*sizeof(int), stream);
    k_hist<<<(EE2+255)/256, 256, 0, stream>>>(dst2, nullptr, cnt2, EE2, NN2, 0);
    k_chunksum<<<nchunk, 256, 0, stream>>>(cnt2, csum, M);
    k_chunkscan<<<1, 256, 0, stream>>>(csum, nchunk);
    k_chunkapply<<<nchunk, 256, 0, stream>>>(cnt2, csum, R2, cnt2, M);
    k_scatter<<<(EE2+255)/256, 256, 0, stream>>>(src2, dst2, nullptr, cnt2, ep2, EE2, NN2, 0);
  }

  // GRU: two 3-slab GEMM launches (round-8 proven structure) + pointwise finalize
  auto gru = [&](float* hbuf, int N, int lidx){
    if (bigpath){
      k_transform4<<<3*1024, 256, 0, stream>>>(aggr, wihT + (size_t)lidx*12288, nullptr, tr, N);
      k_transform4<<<3*1024, 256, 0, stream>>>(hbuf, whhT + (size_t)lidx*12288, nullptr, tr + (size_t)3*N*64, N);
      k_gru_fin<<<(N*16+255)/256, 256, 0, stream>>>(tr, conv_bih + lidx*192, conv_bhh + lidx*192, hbuf, N);
    } else {
      k_gru_old<<<1024, 192, 0, stream>>>(aggr, hbuf,
          conv_wih + (size_t)lidx*12288, conv_whh + (size_t)lidx*12288,
          conv_bih + lidx*192, conv_bhh + lidx*192, N);
    }
  };

  // ---- level-1: 3x MGGC(L=3) + BN + ReLU ----
  for (int i = 0; i < 3; ++i){
    k_coeff<<<(NN1+255)/256, 256, 0, stream>>>(conv_nt + i*9, node_type, coeff, NN1);
    for (int l = 0; l < 3; ++l){
      const float* Wl = conv_w + (size_t)(i*3+l)*4*4096;
      if (bigpath){
        k_transform4<<<4096, 256, 0, stream>>>(h, Wl, coeff, tr, NN1);
        k_sweep_p<<<(NN1+3)/4, 256, 0, stream>>>(tr, R1, ep1, aggr, NN1);
      } else {
        for (int t = 0; t < 4; ++t){
          k_transform4<<<1024, 256, 0, stream>>>(h, Wl + (size_t)t*4096, coeff, tr, NN1);
          k_sweep<<<(NN1+3)/4, 256, 0, stream>>>(tr, R1 + (size_t)t*NN1, ep1, aggr, NN1, t == 0);
        }
      }
      gru(h, NN1, i);
    }
    hipMemsetAsync(stats, 0, 128*sizeof(float), stream);
    k_bnstats<<<256, 256, 0, stream>>>(h, stats, NN1);
    k_bnapply<<<(NN1*64+255)/256, 256, 0, stream>>>(h, stats, bn_g + i*64, bn_b + i*64, NN1, 1);
  }

  // ---- set2set (single fused kernel) ----
  k_set2set<<<256, 256, 0, stream>>>(h, rb1, s1_wih0, s1_whh0, s1_b0, s1_wih1, s1_whh1, s1_b1, x1);

  // ---- avg_pool ----
  hipMemsetAsync(h2, 0, (size_t)NN2*64*sizeof(float), stream);
  hipMemsetAsync(cnt, 0, (size_t)NN2*sizeof(float), stream);
  k_pool_acc<<<(AA*64+255)/256, 256, 0, stream>>>(h, assign_src, assign_dst, h2, cnt, AA);
  k_pool_div<<<(NN2*64+255)/256, 256, 0, stream>>>(h2, cnt, NN2);

  // ---- level-2: 2x relu(MGGC(L=3)) ----
  for (int L = 3; L < 5; ++L){
    for (int l = 0; l < 3; ++l){
      k_transform4<<<1024, 256, 0, stream>>>(h2, conv_w + (size_t)(L*3+l)*4*4096, nullptr, tr, NN2);
      k_sweep_p<<<(NN2+3)/4, 256, 0, stream>>>(tr, R2, ep2, aggr, NN2);
      gru(h2, NN2, L);
    }
    k_relu<<<(NN2*64+255)/256, 256, 0, stream>>>(h2, NN2*64);
  }

  k_set2set<<<256, 256, 0, stream>>>(h2, rb2, s2_wih0, s2_whh0, s2_b0, s2_wih1, s2_whh1, s2_b1, x2);

  // ---- head ----
  k_concat<<<256, 256, 0, stream>>>(x1, x2, z);
  k_bn_par<<<256, 256, 0, stream>>>(z, prebn_g, prebn_b, 256, 0);
  k_fc<<<256, 128, 0, stream>>>(z, fc_w0, fc_b0, z1, 256, 128);
  k_bn_par<<<128, 256, 0, stream>>>(z1, fcbn_g0, fcbn_b0, 128, 1);
  k_fc<<<256, 64, 0, stream>>>(z1, fc_w1, fc_b1, z2, 128, 64);
  k_bn_par<<<64, 256, 0, stream>>>(z2, fcbn_g1, fcbn_b1, 64, 1);
  k_fc_out<<<4, 64, 0, stream>>>(z2, fc_w2, fc_b2, (float*)d_out);
}

// Round 11
// 4639.416 us; speedup vs baseline: 2.0896x; 1.0695x over previous
//
#include <hip/hip_runtime.h>

#define NN1 60000
#define EE1 600000
#define NN2 20000
#define EE2 150000
#define AA  60000

__device__ __forceinline__ float sigf(float x){ return 1.f/(1.f+expf(-x)); }

// ---------- elementwise ----------
__global__ void k_relu(float* a, int n){
  int i = blockIdx.x*blockDim.x + threadIdx.x;
  if (i < n) a[i] = fmaxf(a[i], 0.f);
}
__global__ void k_copy(const float* __restrict__ a, float* __restrict__ o, int n){
  int i = blockIdx.x*blockDim.x + threadIdx.x;
  if (i < n) o[i] = a[i];
}

// ---------- edge type ----------
__global__ void k_etype(const float* __restrict__ ea, int* __restrict__ etype, int E){
  int e = blockIdx.x*blockDim.x + threadIdx.x;
  if (e >= E) return;
  const float* p = ea + (size_t)e*10;
  float best = p[0]; int bi = 0;
  #pragma unroll
  for (int k = 1; k < 4; ++k){ float v = p[k]; if (v > best){ best = v; bi = k; } }
  etype[e] = bi;
}

__global__ void k_coeff(const float* __restrict__ nt, const int* __restrict__ node_type,
                        float* __restrict__ coeff, int N){
  int n = blockIdx.x*blockDim.x + threadIdx.x;
  if (n < N) coeff[n] = nt[node_type[n]];
}

// ---------- batch row pointers (batch sorted ascending) ----------
__global__ void k_batchptr(const int* __restrict__ batch, int* __restrict__ rb, int N, int B){
  int n = blockIdx.x*blockDim.x + threadIdx.x;
  if (n >= N) return;
  int b = batch[n];
  if (n == 0){ for (int g = 0; g <= b; ++g) rb[g] = 0; }
  else {
    int pb = batch[n-1];
    for (int g = pb+1; g <= b; ++g) rb[g] = n;
  }
  if (n == N-1){ for (int g = b+1; g <= B; ++g) rb[g] = N; }
}

// ---------- GRU weight transpose: wih[l][j][c] -> wihT[l][t][c][d], j=64t+d ----------
__global__ void k_wtrans(const float* __restrict__ wih, const float* __restrict__ whh,
                         float* __restrict__ wihT, float* __restrict__ whhT){
  int idx = blockIdx.x*256 + threadIdx.x;   // 5*192*64 = 61440
  if (idx >= 5*192*64) return;
  int l = idx / 12288, r = idx % 12288;
  int j = r >> 6, c = r & 63;
  int t = j >> 6, d = j & 63;
  int dst = l*12288 + t*4096 + c*64 + d;
  wihT[dst] = wih[idx];
  whhT[dst] = whh[idx];
}

// ---------- set2set LSTM weight transpose to [k][j] (coalesced over gate row j) ----------
// layout: T[0:32768)=wih0T[128][256], [32768:49152)=whh0T[64][256],
//         [49152:65536)=wih1T[64][256], [65536:81920)=whh1T[64][256]
__global__ void k_s2strans(const float* __restrict__ wih0, const float* __restrict__ whh0,
                           const float* __restrict__ wih1, const float* __restrict__ whh1,
                           float* __restrict__ T){
  int idx = blockIdx.x*256 + threadIdx.x;
  if (idx < 32768){ int k = idx >> 8, j = idx & 255; T[idx] = wih0[j*128 + k]; }
  else if (idx < 49152){ int r = idx - 32768; int k = r >> 8, j = r & 255; T[idx] = whh0[j*64 + k]; }
  else if (idx < 65536){ int r = idx - 49152; int k = r >> 8, j = r & 255; T[idx] = wih1[j*64 + k]; }
  else if (idx < 81920){ int r = idx - 65536; int k = r >> 8, j = r & 255; T[idx] = whh1[j*64 + k]; }
}

// ---------- CSR build ----------
__global__ void k_hist(const int* __restrict__ dst, const int* __restrict__ etype,
                       int* __restrict__ cnt, int E, int N, int tkey){
  int e = blockIdx.x*blockDim.x + threadIdx.x;
  if (e >= E) return;
  int t = etype ? etype[e] : 0;
  int key = tkey ? (t*N + dst[e]) : dst[e];
  atomicAdd(&cnt[key], 1);
}
__global__ void k_chunksum(const int* __restrict__ cnt, int* __restrict__ csum, int M){
  __shared__ int sh[256];
  int base = blockIdx.x*1024;
  int s = 0;
  for (int i = threadIdx.x; i < 1024; i += 256){
    int idx = base + i;
    if (idx < M) s += cnt[idx];
  }
  sh[threadIdx.x] = s;
  __syncthreads();
  for (int o = 128; o; o >>= 1){
    if (threadIdx.x < o) sh[threadIdx.x] += sh[threadIdx.x + o];
    __syncthreads();
  }
  if (threadIdx.x == 0) csum[blockIdx.x] = sh[0];
}
__global__ void k_chunkscan(int* __restrict__ csum, int nchunk){
  __shared__ int sh[256];
  int i = threadIdx.x;
  int v = (i < nchunk) ? csum[i] : 0;
  sh[i] = v; __syncthreads();
  for (int o = 1; o < 256; o <<= 1){
    int y = (i >= o) ? sh[i-o] : 0;
    __syncthreads();
    sh[i] += y;
    __syncthreads();
  }
  if (i < nchunk) csum[i] = sh[i] - v;
  if (i == 255) csum[nchunk] = sh[255];
}
__global__ void k_chunkapply(const int* __restrict__ cnt, const int* __restrict__ csum,
                             int* __restrict__ R, int* __restrict__ cur, int M){
  __shared__ int sh[256];
  int base = blockIdx.x*1024;
  int i0 = base + threadIdx.x*4;
  int v[4]; int s = 0;
  #pragma unroll
  for (int k = 0; k < 4; ++k){ int idx = i0 + k; v[k] = (idx < M) ? cnt[idx] : 0; s += v[k]; }
  sh[threadIdx.x] = s; __syncthreads();
  for (int o = 1; o < 256; o <<= 1){
    int y = (threadIdx.x >= o) ? sh[threadIdx.x-o] : 0;
    __syncthreads();
    sh[threadIdx.x] += y;
    __syncthreads();
  }
  int run = csum[blockIdx.x] + sh[threadIdx.x] - s;
  #pragma unroll
  for (int k = 0; k < 4; ++k){
    int idx = i0 + k;
    if (idx < M){ R[idx] = run; cur[idx] = run; run += v[k]; }
  }
  if (threadIdx.x == 255 && base + 1024 >= M) R[M] = csum[blockIdx.x] + sh[255];
}
__global__ void k_scatter(const int* __restrict__ src, const int* __restrict__ dst,
                          const int* __restrict__ etype, int* __restrict__ cur,
                          int* __restrict__ ep, int E, int N, int tkey){
  int e = blockIdx.x*blockDim.x + threadIdx.x;
  if (e >= E) return;
  int t = etype ? etype[e] : 0;
  int key = tkey ? (t*N + dst[e]) : dst[e];
  int pos = atomicAdd(&cur[key], 1);
  ep[pos] = (t << 20) | src[e];
}

// ---------- transform: tr[t][n][d] = coeff[n] * sum_c X[n][c]*W[t][c][d] ----------
// launch_bounds(256,3): ~170 VGPR budget so the 64 weights + row buffer stay
// register-resident (VGPR 44 in r10 proved the compiler was re-loading weights
// from L1 every node -> 80 VMEM/node; this gets it to 17 VMEM/node).
__global__ __launch_bounds__(256, 3) void k_transform4(
                             const float* __restrict__ h, const float* __restrict__ W,
                             const float* __restrict__ coeff, float* __restrict__ tr, int N){
  int t = blockIdx.x >> 10, blk = blockIdx.x & 1023;
  int d = threadIdx.x & 63, sub = threadIdx.x >> 6;
  float4 wreg[16];
  const float* Wt = W + (size_t)t*4096;
  #pragma unroll
  for (int c = 0; c < 16; ++c){
    wreg[c].x = Wt[(4*c+0)*64 + d];
    wreg[c].y = Wt[(4*c+1)*64 + d];
    wreg[c].z = Wt[(4*c+2)*64 + d];
    wreg[c].w = Wt[(4*c+3)*64 + d];
  }
  for (int n = blk*4 + sub; n < N; n += 4096){
    const float4* hr = (const float4*)(h + (size_t)n*64);
    float4 v[16];
    #pragma unroll
    for (int c = 0; c < 16; ++c) v[c] = hr[c];
    float a0 = 0.f, a1 = 0.f, a2 = 0.f, a3 = 0.f;
    #pragma unroll
    for (int c = 0; c < 16; ++c){
      a0 = fmaf(v[c].x, wreg[c].x, a0);
      a1 = fmaf(v[c].y, wreg[c].y, a1);
      a2 = fmaf(v[c].z, wreg[c].z, a2);
      a3 = fmaf(v[c].w, wreg[c].w, a3);
    }
    float acc = (a0 + a1) + (a2 + a3);
    if (coeff) acc *= coeff[n];
    tr[((size_t)t*N + n)*64 + d] = acc;
  }
}

// ---------- merged sweep ----------
__global__ void k_sweep_p(const float* __restrict__ tr, const int* __restrict__ R,
                          const int* __restrict__ ep, float* __restrict__ aggr, int N){
  int w = threadIdx.x >> 6, lane = threadIdx.x & 63;
  int d = blockIdx.x*4 + w;
  if (d >= N) return;
  int p = R[d], pend = R[d+1];
  float acc = 0.f;
  while (p < pend){
    int m = pend - p; if (m > 64) m = 64;
    int ev = (lane < m) ? ep[p + lane] : 0;
    for (int j = 0; j < m; ++j){
      int pk = __shfl(ev, j);
      int s = pk & 0xFFFFF, t = pk >> 20;
      acc += tr[((size_t)t*N + s)*64 + lane];
    }
    p += m;
  }
  aggr[(size_t)d*64 + lane] = acc;
}
__global__ void k_sweep(const float* __restrict__ tr, const int* __restrict__ R,
                        const int* __restrict__ ep, float* __restrict__ aggr,
                        int N, int first){
  int w = threadIdx.x >> 6, lane = threadIdx.x & 63;
  int d = blockIdx.x*4 + w;
  if (d >= N) return;
  int p = R[d], pend = R[d+1];
  float acc = first ? 0.f : aggr[(size_t)d*64 + lane];
  while (p < pend){
    int m = pend - p; if (m > 64) m = 64;
    int ev = (lane < m) ? ep[p + lane] : 0;
    for (int j = 0; j < m; ++j){
      int s = __shfl(ev, j) & 0xFFFFF;
      acc += tr[(size_t)s*64 + lane];
    }
    p += m;
  }
  aggr[(size_t)d*64 + lane] = acc;
}

// ---------- GRU finalize: gb = [gi_r, gi_z, gi_n, gh_r, gh_z, gh_n] slabs of [N][64] ----------
__global__ void k_gru_fin(const float* __restrict__ gb,
                          const float* __restrict__ bih, const float* __restrict__ bhh,
                          float* __restrict__ h, int N){
  int i = blockIdx.x*256 + threadIdx.x;     // over N*16 float4 slots
  if (i >= N*16) return;
  int q = i & 15;
  const float4* g4 = (const float4*)gb;
  size_t S = (size_t)N*16;
  float4 gi0 = g4[i], gi1 = g4[S + i], gi2 = g4[2*S + i];
  float4 gh0 = g4[3*S + i], gh1 = g4[4*S + i], gh2 = g4[5*S + i];
  const float4* bi4 = (const float4*)bih;
  const float4* bh4 = (const float4*)bhh;
  float4 bir = bi4[q],    bhr = bh4[q];
  float4 biz = bi4[16+q], bhz = bh4[16+q];
  float4 bin = bi4[32+q], bhn = bh4[32+q];
  float4* h4 = (float4*)h;
  float4 hv = h4[i];
  float4 out;
  {
    float r = sigf(gi0.x + gh0.x + bir.x + bhr.x);
    float z = sigf(gi1.x + gh1.x + biz.x + bhz.x);
    float nn = tanhf(gi2.x + bin.x + r*(gh2.x + bhn.x));
    out.x = (1.f - z)*nn + z*hv.x;
  }
  {
    float r = sigf(gi0.y + gh0.y + bir.y + bhr.y);
    float z = sigf(gi1.y + gh1.y + biz.y + bhz.y);
    float nn = tanhf(gi2.y + bin.y + r*(gh2.y + bhn.y));
    out.y = (1.f - z)*nn + z*hv.y;
  }
  {
    float r = sigf(gi0.z + gh0.z + bir.z + bhr.z);
    float z = sigf(gi1.z + gh1.z + biz.z + bhz.z);
    float nn = tanhf(gi2.z + bin.z + r*(gh2.z + bhn.z));
    out.z = (1.f - z)*nn + z*hv.z;
  }
  {
    float r = sigf(gi0.w + gh0.w + bir.w + bhr.w);
    float z = sigf(gi1.w + gh1.w + biz.w + bhz.w);
    float nn = tanhf(gi2.w + bin.w + r*(gh2.w + bhn.w));
    out.w = (1.f - z)*nn + z*hv.w;
  }
  h4[i] = out;
}

// ---------- GRU fallback ----------
__global__ void k_gru_old(const float* __restrict__ aggr, float* __restrict__ h,
                      const float* __restrict__ wih, const float* __restrict__ whh,
                      const float* __restrict__ bih, const float* __restrict__ bhh, int N){
  int j = threadIdx.x;
  float4 wi4[16], wh4[16];
  const float4* wisrc = (const float4*)(wih + (size_t)j*64);
  const float4* whsrc = (const float4*)(whh + (size_t)j*64);
  #pragma unroll
  for (int c = 0; c < 16; ++c){ wi4[c] = wisrc[c]; wh4[c] = whsrc[c]; }
  float bi = bih[j], bh = bhh[j];
  __shared__ float gi_s[192], gh_s[192];
  for (int n = blockIdx.x; n < N; n += gridDim.x){
    const float4* mr = (const float4*)(aggr + (size_t)n*64);
    const float4* hr = (const float4*)(h + (size_t)n*64);
    float ai = bi, ah = bh;
    #pragma unroll
    for (int c = 0; c < 16; ++c){
      float4 m4 = mr[c], h4 = hr[c];
      ai = fmaf(m4.x, wi4[c].x, ai); ah = fmaf(h4.x, wh4[c].x, ah);
      ai = fmaf(m4.y, wi4[c].y, ai); ah = fmaf(h4.y, wh4[c].y, ah);
      ai = fmaf(m4.z, wi4[c].z, ai); ah = fmaf(h4.z, wh4[c].z, ah);
      ai = fmaf(m4.w, wi4[c].w, ai); ah = fmaf(h4.w, wh4[c].w, ah);
    }
    gi_s[j] = ai; gh_s[j] = ah;
    __syncthreads();
    if (j < 64){
      float r  = sigf(gi_s[j]      + gh_s[j]);
      float z  = sigf(gi_s[64+j]   + gh_s[64+j]);
      float nn = tanhf(gi_s[128+j] + r*gh_s[128+j]);
      h[(size_t)n*64 + j] = (1.f - z)*nn + z*h[(size_t)n*64 + j];
    }
    __syncthreads();
  }
}

// ---------- batch norm over nodes ----------
__global__ void k_bnstats(const float* __restrict__ h, float* __restrict__ stats, int N){
  int c = threadIdx.x & 63;
  int g = threadIdx.x >> 6;
  float s = 0.f, s2 = 0.f;
  for (int n = blockIdx.x*4 + g; n < N; n += gridDim.x*4){
    float v = h[(size_t)n*64 + c]; s += v; s2 += v*v;
  }
  __shared__ float sh[4][64], sh2[4][64];
  sh[g][c] = s; sh2[g][c] = s2;
  __syncthreads();
  if (g == 0){
    float ts = sh[0][c]+sh[1][c]+sh[2][c]+sh[3][c];
    float t2 = sh2[0][c]+sh2[1][c]+sh2[2][c]+sh2[3][c];
    atomicAdd(&stats[c], ts); atomicAdd(&stats[64+c], t2);
  }
}
__global__ void k_bnapply(float* __restrict__ h, const float* __restrict__ stats,
                          const float* __restrict__ g, const float* __restrict__ b,
                          int N, int relu){
  int i = blockIdx.x*blockDim.x + threadIdx.x;
  if (i >= N*64) return;
  int c = i & 63;
  float inv = 1.f/(float)N;
  float mean = stats[c]*inv;
  float var  = stats[64+c]*inv - mean*mean;
  float y = (h[i]-mean)*rsqrtf(var + 1e-5f)*g[c] + b[c];
  if (relu) y = fmaxf(y, 0.f);
  h[i] = y;
}

// ---------- avg_pool ----------
__global__ void k_pool_acc(const float* __restrict__ h, const int* __restrict__ asrc,
                           const int* __restrict__ adst, float* __restrict__ h2,
                           float* __restrict__ cnt, int A){
  int i = blockIdx.x*blockDim.x + threadIdx.x;
  if (i >= A*64) return;
  int a = i >> 6, c = i & 63;
  int s = asrc[a], d = adst[a];
  atomicAdd(&h2[(size_t)d*64 + c], h[(size_t)s*64 + c]);
  if (c == 0) atomicAdd(&cnt[d], 1.f);
}
__global__ void k_pool_div(float* __restrict__ h2, const float* __restrict__ cnt, int N){
  int i = blockIdx.x*blockDim.x + threadIdx.x;
  if (i >= N*64) return;
  h2[i] = h2[i] / fmaxf(cnt[i >> 6], 1.f);
}

// ---------- fully fused set2set: one block (1024 thr = 16 waves) per graph ----------
// T = transposed LSTM weights (coalesced over gate row j)
__global__ __launch_bounds__(1024) void k_set2set(const float* __restrict__ x, const int* __restrict__ rb,
                          const float* __restrict__ T,
                          const float* __restrict__ b0, const float* __restrict__ b1,
                          float* __restrict__ xout){
  int b = blockIdx.x, j = threadIdx.x;
  int w = j >> 6, lane = j & 63;
  __shared__ float qstar[128], h0[64], c0[64], h1[64], c1[64];
  __shared__ float gs[256], wmax[16], wsum[16], racc[16][64];
  if (j < 128) qstar[j] = 0.f;
  if (j < 64){ h0[j] = 0.f; c0[j] = 0.f; h1[j] = 0.f; c1[j] = 0.f; }
  __syncthreads();
  int n0 = rb[b], n1 = rb[b+1];
  const float* T0 = T;            // wih0T [128][256]
  const float* T1 = T + 32768;    // whh0T [64][256]
  const float* T2 = T + 49152;    // wih1T [64][256]
  const float* T3 = T + 65536;    // whh1T [64][256]
  for (int s = 0; s < 5; ++s){
    // LSTM0: gate rows j<256, input qstar[128], hidden h0[64]; coalesced T reads
    if (j < 256){
      float a0 = b0[j], a1 = 0.f, a2 = 0.f, a3 = 0.f;
      #pragma unroll 4
      for (int k = 0; k < 128; k += 4){
        a0 = fmaf(T0[(k+0)*256 + j], qstar[k+0], a0);
        a1 = fmaf(T0[(k+1)*256 + j], qstar[k+1], a1);
        a2 = fmaf(T0[(k+2)*256 + j], qstar[k+2], a2);
        a3 = fmaf(T0[(k+3)*256 + j], qstar[k+3], a3);
      }
      #pragma unroll 4
      for (int k = 0; k < 64; k += 4){
        a0 = fmaf(T1[(k+0)*256 + j], h0[k+0], a0);
        a1 = fmaf(T1[(k+1)*256 + j], h0[k+1], a1);
        a2 = fmaf(T1[(k+2)*256 + j], h0[k+2], a2);
        a3 = fmaf(T1[(k+3)*256 + j], h0[k+3], a3);
      }
      gs[j] = (a0 + a1) + (a2 + a3);
    }
    __syncthreads();
    if (j < 64){
      float ig = sigf(gs[j]);
      float fg = sigf(gs[64+j]);
      float gg = tanhf(gs[128+j]);
      float og = sigf(gs[192+j]);
      float cn = fg*c0[j] + ig*gg;
      c0[j] = cn;
      h0[j] = og*tanhf(cn);
    }
    __syncthreads();
    // LSTM1: input h0 (new), hidden h1 (old)
    if (j < 256){
      float a0 = b1[j], a1 = 0.f, a2 = 0.f, a3 = 0.f;
      #pragma unroll 4
      for (int k = 0; k < 64; k += 4){
        a0 = fmaf(T2[(k+0)*256 + j], h0[k+0], a0);
        a1 = fmaf(T2[(k+1)*256 + j], h0[k+1], a1);
        a2 = fmaf(T2[(k+2)*256 + j], h0[k+2], a2);
        a3 = fmaf(T2[(k+3)*256 + j], h0[k+3], a3);
      }
      #pragma unroll 4
      for (int k = 0; k < 64; k += 4){
        a0 = fmaf(T3[(k+0)*256 + j], h1[k+0], a0);
        a1 = fmaf(T3[(k+1)*256 + j], h1[k+1], a1);
        a2 = fmaf(T3[(k+2)*256 + j], h1[k+2], a2);
        a3 = fmaf(T3[(k+3)*256 + j], h1[k+3], a3);
      }
      gs[j] = (a0 + a1) + (a2 + a3);
    }
    __syncthreads();
    if (j < 64){
      float ig = sigf(gs[j]);
      float fg = sigf(gs[64+j]);
      float gg = tanhf(gs[128+j]);
      float og = sigf(gs[192+j]);
      float cn = fg*c1[j] + ig*gg;
      c1[j] = cn;
      float hn = og*tanhf(cn);
      h1[j] = hn;
      qstar[j] = hn;          // q half of q_star
    }
    __syncthreads();
    // attention over [n0,n1): softmax(x·q) then r = sum a*x; 16 waves stride
    float lmax = -3.4e38f;
    for (int n = n0 + w; n < n1; n += 16){
      float v = x[(size_t)n*64 + lane]*qstar[lane];
      #pragma unroll
      for (int o = 32; o; o >>= 1) v += __shfl_xor(v, o);
      lmax = fmaxf(lmax, v);
    }
    if (lane == 0) wmax[w] = lmax;
    __syncthreads();
    float bmax = wmax[0];
    #pragma unroll
    for (int k = 1; k < 16; ++k) bmax = fmaxf(bmax, wmax[k]);
    float lsum = 0.f, lr = 0.f;
    for (int n = n0 + w; n < n1; n += 16){
      float xv = x[(size_t)n*64 + lane];
      float v = xv*qstar[lane];
      #pragma unroll
      for (int o = 32; o; o >>= 1) v += __shfl_xor(v, o);
      float wexp = expf(v - bmax);
      lsum += wexp;
      lr = fmaf(wexp, xv, lr);
    }
    if (lane == 0) wsum[w] = lsum;
    racc[w][lane] = lr;
    __syncthreads();
    if (j < 64){
      float r = 0.f, denom = 0.f;
      #pragma unroll
      for (int k = 0; k < 16; ++k){ r += racc[k][j]; denom += wsum[k]; }
      qstar[64 + j] = (denom > 0.f) ? (r/denom) : 0.f;
    }
    __syncthreads();
  }
  if (j < 128) xout[(size_t)b*128 + j] = qstar[j];
}

// ---------- head ----------
__global__ void k_concat(const float* __restrict__ x1, const float* __restrict__ x2,
                         float* __restrict__ z){
  int i = blockIdx.x*blockDim.x + threadIdx.x;
  if (i >= 256*256) return;
  int b = i >> 8, c = i & 255;
  z[i] = (c < 128) ? x1[b*128 + c] : x2[b*128 + (c - 128)];
}
__global__ void k_bn_par(float* __restrict__ X, const float* __restrict__ g,
                         const float* __restrict__ b, int F, int relu){
  int f = blockIdx.x, i = threadIdx.x;
  float v = X[(size_t)i*F + f];
  __shared__ float s1[256], s2[256];
  s1[i] = v; s2[i] = v*v;
  __syncthreads();
  for (int o = 128; o; o >>= 1){
    if (i < o){ s1[i] += s1[i+o]; s2[i] += s2[i+o]; }
    __syncthreads();
  }
  float mean = s1[0]*(1.f/256.f);
  float var  = s2[0]*(1.f/256.f) - mean*mean;
  float y = (v - mean)*rsqrtf(var + 1e-5f)*g[f] + b[f];
  if (relu) y = fmaxf(y, 0.f);
  X[(size_t)i*F + f] = y;
}
__global__ void k_fc(const float* __restrict__ X, const float* __restrict__ W,
                     const float* __restrict__ bias, float* __restrict__ Y, int K, int F){
  int b = blockIdx.x, f = threadIdx.x;
  if (f >= F) return;
  const float* xr = X + (size_t)b*K;
  const float* wr = W + (size_t)f*K;
  float acc = bias[f];
  for (int k = 0; k < K; ++k) acc = fmaf(xr[k], wr[k], acc);
  Y[(size_t)b*F + f] = acc;
}
__global__ void k_fc_out(const float* __restrict__ z2, const float* __restrict__ w,
                         const float* __restrict__ bias, float* __restrict__ out){
  int b = blockIdx.x*blockDim.x + threadIdx.x;
  if (b >= 256) return;
  float acc = bias[0];
  #pragma unroll
  for (int k = 0; k < 64; ++k) acc = fmaf(z2[b*64 + k], w[k], acc);
  out[b] = acc;
}

extern "C" void kernel_launch(void* const* d_in, const int* in_sizes, int n_in,
                              void* d_out, int out_size, void* d_ws, size_t ws_size,
                              hipStream_t stream) {
  const float* x_in     = (const float*)d_in[0];
  const float* edge_attr= (const float*)d_in[1];
  const float* conv_w   = (const float*)d_in[2];
  const float* conv_wih = (const float*)d_in[3];
  const float* conv_whh = (const float*)d_in[4];
  const float* conv_bih = (const float*)d_in[5];
  const float* conv_bhh = (const float*)d_in[6];
  const float* conv_nt  = (const float*)d_in[7];
  const float* s1_wih0 = (const float*)d_in[8];
  const float* s1_whh0 = (const float*)d_in[9];
  const float* s1_b0   = (const float*)d_in[10];
  const float* s1_wih1 = (const float*)d_in[11];
  const float* s1_whh1 = (const float*)d_in[12];
  const float* s1_b1   = (const float*)d_in[13];
  const float* s2_wih0 = (const float*)d_in[14];
  const float* s2_whh0 = (const float*)d_in[15];
  const float* s2_b0   = (const float*)d_in[16];
  const float* s2_wih1 = (const float*)d_in[17];
  const float* s2_whh1 = (const float*)d_in[18];
  const float* s2_b1   = (const float*)d_in[19];
  const float* bn_g    = (const float*)d_in[20];
  const float* bn_b    = (const float*)d_in[21];
  const float* prebn_g = (const float*)d_in[22];
  const float* prebn_b = (const float*)d_in[23];
  const float* fc_w0   = (const float*)d_in[24];
  const float* fc_b0   = (const float*)d_in[25];
  const float* fc_w1   = (const float*)d_in[26];
  const float* fc_b1   = (const float*)d_in[27];
  const float* fc_w2   = (const float*)d_in[28];
  const float* fc_b2   = (const float*)d_in[29];
  const float* fcbn_g0 = (const float*)d_in[30];
  const float* fcbn_b0 = (const float*)d_in[31];
  const float* fcbn_g1 = (const float*)d_in[32];
  const float* fcbn_b1 = (const float*)d_in[33];
  const int* edge_index   = (const int*)d_in[34];
  const int* node_type    = (const int*)d_in[35];
  const int* batch        = (const int*)d_in[36];
  const int* assign_src   = (const int*)d_in[37];
  const int* assign_dst   = (const int*)d_in[38];
  const int* edge_index_2 = (const int*)d_in[39];
  const int* batch_2      = (const int*)d_in[40];
  (void)in_sizes; (void)n_in; (void)out_size;

  // ---- workspace layout ----
  float* Wp = (float*)d_ws;
  float *h, *tr, *aggr, *coeff, *h2, *cnt;
  float *x1, *x2, *z, *z1, *z2, *stats, *wihT, *whhT, *s2sT1, *s2sT2;
  int *etype, *cnt1, *R1, *ep1, *cnt2, *R2, *ep2, *csum, *rb1, *rb2;
  size_t o = 0;
  auto layout = [&](size_t trsize){
    o = 0;
    auto alloc = [&](size_t n){ float* p = Wp + o; o += n; return p; };
    h     = alloc((size_t)NN1*64);
    tr    = alloc(trsize);
    aggr  = alloc((size_t)NN1*64);
    coeff = alloc(NN1);
    h2    = alloc((size_t)NN2*64);
    cnt   = alloc(NN2);
    x1    = alloc(256*128);
    x2    = alloc(256*128);
    z     = alloc(256*256);
    z1    = alloc(256*128);
    z2    = alloc(256*64);
    stats = alloc(128);
    wihT  = alloc(5*12288);
    whhT  = alloc(5*12288);
    s2sT1 = alloc(81920);
    s2sT2 = alloc(81920);
    etype = (int*)alloc(EE1);
    cnt1  = (int*)alloc(4*NN1);
    R1    = (int*)alloc(4*NN1 + 1);
    ep1   = (int*)alloc(EE1);
    cnt2  = (int*)alloc(NN2);
    R2    = (int*)alloc(NN2 + 1);
    ep2   = (int*)alloc(EE2);
    csum  = (int*)alloc(260);
    rb1   = (int*)alloc(257);
    rb2   = (int*)alloc(257);
  };
  layout((size_t)6*NN1*64);
  int bigpath = (o*sizeof(float) <= ws_size);
  if (!bigpath) layout((size_t)NN1*64);

  const int* src1 = edge_index;
  const int* dst1 = edge_index + EE1;
  const int* src2 = edge_index_2;
  const int* dst2 = edge_index_2 + EE2;

  k_etype<<<(EE1+255)/256, 256, 0, stream>>>(edge_attr, etype, EE1);
  k_copy<<<(NN1*64+255)/256, 256, 0, stream>>>(x_in, h, NN1*64);
  k_wtrans<<<(5*12288+255)/256, 256, 0, stream>>>(conv_wih, conv_whh, wihT, whhT);
  k_s2strans<<<(81920+255)/256, 256, 0, stream>>>(s1_wih0, s1_whh0, s1_wih1, s1_whh1, s2sT1);
  k_s2strans<<<(81920+255)/256, 256, 0, stream>>>(s2_wih0, s2_whh0, s2_wih1, s2_whh1, s2sT2);
  k_batchptr<<<(NN1+255)/256, 256, 0, stream>>>(batch, rb1, NN1, 256);
  k_batchptr<<<(NN2+255)/256, 256, 0, stream>>>(batch_2, rb2, NN2, 256);

  {  // level-1 CSR
    int M = bigpath ? NN1 : 4*NN1;
    int nchunk = (M + 1023)/1024;
    hipMemsetAsync(cnt1, 0, (size_t)M*sizeof(int), stream);
    k_hist<<<(EE1+255)/256, 256, 0, stream>>>(dst1, etype, cnt1, EE1, NN1, !bigpath);
    k_chunksum<<<nchunk, 256, 0, stream>>>(cnt1, csum, M);
    k_chunkscan<<<1, 256, 0, stream>>>(csum, nchunk);
    k_chunkapply<<<nchunk, 256, 0, stream>>>(cnt1, csum, R1, cnt1, M);
    k_scatter<<<(EE1+255)/256, 256, 0, stream>>>(src1, dst1, etype, cnt1, ep1, EE1, NN1, !bigpath);
  }
  {  // level-2 CSR
    int M = NN2, nchunk = (M + 1023)/1024;
    hipMemsetAsync(cnt2, 0, (size_t)M*sizeof(int), stream);
    k_hist<<<(EE2+255)/256, 256, 0, stream>>>(dst2, nullptr, cnt2, EE2, NN2, 0);
    k_chunksum<<<nchunk, 256, 0, stream>>>(cnt2, csum, M);
    k_chunkscan<<<1, 256, 0, stream>>>(csum, nchunk);
    k_chunkapply<<<nchunk, 256, 0, stream>>>(cnt2, csum, R2, cnt2, M);
    k_scatter<<<(EE2+255)/256, 256, 0, stream>>>(src2, dst2, nullptr, cnt2, ep2, EE2, NN2, 0);
  }

  // GRU: two 3-slab GEMM launches + pointwise finalize
  auto gru = [&](float* hbuf, int N, int lidx){
    if (bigpath){
      k_transform4<<<3*1024, 256, 0, stream>>>(aggr, wihT + (size_t)lidx*12288, nullptr, tr, N);
      k_transform4<<<3*1024, 256, 0, stream>>>(hbuf, whhT + (size_t)lidx*12288, nullptr, tr + (size_t)3*N*64, N);
      k_gru_fin<<<(N*16+255)/256, 256, 0, stream>>>(tr, conv_bih + lidx*192, conv_bhh + lidx*192, hbuf, N);
    } else {
      k_gru_old<<<1024, 192, 0, stream>>>(aggr, hbuf,
          conv_wih + (size_t)lidx*12288, conv_whh + (size_t)lidx*12288,
          conv_bih + lidx*192, conv_bhh + lidx*192, N);
    }
  };

  // ---- level-1: 3x MGGC(L=3) + BN + ReLU ----
  for (int i = 0; i < 3; ++i){
    k_coeff<<<(NN1+255)/256, 256, 0, stream>>>(conv_nt + i*9, node_type, coeff, NN1);
    for (int l = 0; l < 3; ++l){
      const float* Wl = conv_w + (size_t)(i*3+l)*4*4096;
      if (bigpath){
        k_transform4<<<4096, 256, 0, stream>>>(h, Wl, coeff, tr, NN1);
        k_sweep_p<<<(NN1+3)/4, 256, 0, stream>>>(tr, R1, ep1, aggr, NN1);
      } else {
        for (int t = 0; t < 4; ++t){
          k_transform4<<<1024, 256, 0, stream>>>(h, Wl + (size_t)t*4096, coeff, tr, NN1);
          k_sweep<<<(NN1+3)/4, 256, 0, stream>>>(tr, R1 + (size_t)t*NN1, ep1, aggr, NN1, t == 0);
        }
      }
      gru(h, NN1, i);
    }
    hipMemsetAsync(stats, 0, 128*sizeof(float), stream);
    k_bnstats<<<256, 256, 0, stream>>>(h, stats, NN1);
    k_bnapply<<<(NN1*64+255)/256, 256, 0, stream>>>(h, stats, bn_g + i*64, bn_b + i*64, NN1, 1);
  }

  // ---- set2set (single fused kernel, 1024 threads/graph) ----
  k_set2set<<<256, 1024, 0, stream>>>(h, rb1, s2sT1, s1_b0, s1_b1, x1);

  // ---- avg_pool ----
  hipMemsetAsync(h2, 0, (size_t)NN2*64*sizeof(float), stream);
  hipMemsetAsync(cnt, 0, (size_t)NN2*sizeof(float), stream);
  k_pool_acc<<<(AA*64+255)/256, 256, 0, stream>>>(h, assign_src, assign_dst, h2, cnt, AA);
  k_pool_div<<<(NN2*64+255)/256, 256, 0, stream>>>(h2, cnt, NN2);

  // ---- level-2: 2x relu(MGGC(L=3)) ----
  for (int L = 3; L < 5; ++L){
    for (int l = 0; l < 3; ++l){
      k_transform4<<<1024, 256, 0, stream>>>(h2, conv_w + (size_t)(L*3+l)*4*4096, nullptr, tr, NN2);
      k_sweep_p<<<(NN2+3)/4, 256, 0, stream>>>(tr, R2, ep2, aggr, NN2);
      gru(h2, NN2, L);
    }
    k_relu<<<(NN2*64+255)/256, 256, 0, stream>>>(h2, NN2*64);
  }

  k_set2set<<<256, 1024, 0, stream>>>(h2, rb2, s2sT2, s2_b0, s2_b1, x2);

  // ---- head ----
  k_concat<<<256, 256, 0, stream>>>(x1, x2, z);
  k_bn_par<<<256, 256, 0, stream>>>(z, prebn_g, prebn_b, 256, 0);
  k_fc<<<256, 128, 0, stream>>>(z, fc_w0, fc_b0, z1, 256, 128);
  k_bn_par<<<128, 256, 0, stream>>>(z1, fcbn_g0, fcbn_b0, 128, 1);
  k_fc<<<256, 64, 0, stream>>>(z1, fc_w1, fc_b1, z2, 128, 64);
  k_bn_par<<<64, 256, 0, stream>>>(z2, fcbn_g1, fcbn_b1, 64, 1);
  k_fc_out<<<4, 64, 0, stream>>>(z2, fc_w2, fc_b2, (float*)d_out);
}